// Round 16
// baseline (1503.934 us; speedup 1.0000x reference)
//
#include <hip/hip_runtime.h>
#include <hip/hip_bf16.h>

typedef __bf16 bf16_t;
typedef bf16_t bf16x4 __attribute__((ext_vector_type(4)));
typedef bf16_t bf16x8 __attribute__((ext_vector_type(8)));
typedef float  f32x4  __attribute__((ext_vector_type(4)));
typedef _Float16 half4 __attribute__((ext_vector_type(4)));
typedef _Float16 half8 __attribute__((ext_vector_type(8)));

// Problem constants
#define L_  1024
#define N_  16
#define S_  16384          // L*N tokens
#define D_  1024
#define H_  4
#define HD_ 256
#define E_  8
#define FF_ 4096
#define CAP_ 2048
#define ESLOTS_ (E_*CAP_)  // 16384
#define TAU_ 0.03f         // borderline gate-gap threshold

// ---------------------------------------------------------------------------
// async global->LDS, 16B per lane: dest = ldsbase + lane*16 (wave-uniform base)
// ---------------------------------------------------------------------------
__device__ __forceinline__ void gload16(const void* g, void* l) {
  __builtin_amdgcn_global_load_lds(
      (const __attribute__((address_space(1))) void*)g,
      (__attribute__((address_space(3))) void*)l,
      16, 0, 0);
}

// LDS bank swizzle (verified R10: conflicts -> 0). inverse-swizzled SOURCE +
// swizzled READ, LDS stays linear for global_load_lds.
#define SRC_SWZ(lane) (((lane) & 3) ^ (((lane) >> 3) & 3))

// ---------------------------------------------------------------------------
// split2: fp32 -> f16 two-limb (hi, lo*4096)
// ---------------------------------------------------------------------------
__global__ __launch_bounds__(256) void split2(
    const float* __restrict__ in, _Float16* __restrict__ oh,
    _Float16* __restrict__ ol, long n4)
{
  long i = (long)blockIdx.x * blockDim.x + threadIdx.x;
  long stride = (long)gridDim.x * blockDim.x;
  for (; i < n4; i += stride) {
    float4 v = ((const float4*)in)[i];
    half4 h, l;
    h.x = (_Float16)v.x; l.x = (_Float16)((v.x - (float)h.x) * 4096.0f);
    h.y = (_Float16)v.y; l.y = (_Float16)((v.y - (float)h.y) * 4096.0f);
    h.z = (_Float16)v.z; l.z = (_Float16)((v.z - (float)h.z) * 4096.0f);
    h.w = (_Float16)v.w; l.w = (_Float16)((v.w - (float)h.w) * 4096.0f);
    ((half4*)oh)[i] = h;
    ((half4*)ol)[i] = l;
  }
}

// ---------------------------------------------------------------------------
// MFMA GEMM on pre-split f16 limbs.
// PROD==3: C = Ah*Bh + (Ah*Bl + Al*Bh)/4096  (fp32-class)
// PROD==1: C = Ah*Bh                          (f16-class, 1/3 MFMA, 1/2 LDS)
// Block 128x64, K-step 32, 4 waves (2x2), per-wave 64x32, bank-swizzled LDS.
// 3-STAGE COUNTED-VMCNT PIPELINE (both PROD paths, R16): triple-buffer LDS;
// iter t issues tile t+2, computes tile t, drains only tile t+1 (vmcnt=nch,
// that wave's in-flight chunk count for one tile), raw s_barrier -> loads
// stay in flight across barriers (T4).  Requires K >= 64 (all sites K>=256).
// LDS: PROD==3 72KB (2 blocks/CU), PROD==1 36KB (4 blocks/CU).
// EPI: 0 fp32 C; 1 limb-pair C; 2 qkv special; 3 f16-only.
// Row-block = blockIdx.Y, col-block = blockIdx.X (L2 locality, R13).
// ---------------------------------------------------------------------------
template<int EPI, bool HAS_BIAS, int PROD>
__global__ __launch_bounds__(256) void hgemm3s(
    const _Float16* __restrict__ Ah, const _Float16* __restrict__ Al,
    const _Float16* __restrict__ Bh, const _Float16* __restrict__ Bl,
    float* __restrict__ Cf, _Float16* __restrict__ Ch, _Float16* __restrict__ Cl,
    const float* __restrict__ bias,
    int K, long lda, long ldb, long ldcf, long ldch,
    int Z2, long sA1, long sA2, long sB1, long sB2, long sC1, long sC2, long sBias)
{
  constexpr int NL = (PROD == 3) ? 2 : 1;
  __shared__ _Float16 tA[NL][3][128 * 32];
  __shared__ _Float16 tB[NL][3][64 * 32];
  const int z  = blockIdx.z;
  const int z1 = z / Z2, z2 = z - z1 * Z2;
  const long aoff = (long)z1 * sA1 + (long)z2 * sA2;
  const long boff = (long)z1 * sB1 + (long)z2 * sB2;
  const long coff = (long)z1 * sC1 + (long)z2 * sC2;
  const int brow = blockIdx.y * 128, bcol = blockIdx.x * 64;
  const int tid = threadIdx.x, lane = tid & 63, wid = tid >> 6;
  const int wr = (wid >> 1) * 64, wc = (wid & 1) * 32;
  const int fr = lane & 15;
  const int fqs = (((lane >> 4) ^ ((fr >> 1) & 3)) * 8);

  // staging roles
  const bool isA = (wid < 2);
  int limb, dstoff, nch;
  const _Float16* ssrc;
  if constexpr (PROD == 3) {
    limb = wid & 1; nch = isA ? 8 : 4; dstoff = 0;
    ssrc = (wid == 0) ? Ah : (wid == 1) ? Al : (wid == 2) ? Bh : Bl;
  } else {
    limb = 0; nch = isA ? 4 : 2; dstoff = (wid & 1) * nch;
    ssrc = isA ? Ah : Bh;
  }
  const long sld = isA ? lda : ldb;
  const long soff = isA ? aoff : boff;
  int srow = (isA ? brow : bcol) + (lane >> 2);
  if constexpr (PROD == 1) srow += (wid & 1) * (isA ? 64 : 32);
  const _Float16* sbase = ssrc + soff + (long)srow * sld + SRC_SWZ(lane) * 8;

  f32x4 acc0[4][2], acc1[4][2];
#pragma unroll
  for (int mi = 0; mi < 4; ++mi)
#pragma unroll
    for (int ni = 0; ni < 2; ++ni) {
      acc0[mi][ni] = f32x4{0.f, 0.f, 0.f, 0.f};
      acc1[mi][ni] = f32x4{0.f, 0.f, 0.f, 0.f};
    }

  const int NT = K >> 5;

  // prologue: issue tiles 0 and 1; drain tile 0 only (tile 1 stays in flight)
  for (int tt = 0; tt < 2; ++tt) {
    _Float16* d = (isA ? &tA[limb][tt][0] : &tB[limb][tt][0]) + dstoff * 512;
    for (int i = 0; i < nch; ++i)
      gload16(sbase + (long)(16 * i) * sld + tt * 32, d + i * 512);
  }
  if constexpr (PROD == 3) {
    if (isA) asm volatile("s_waitcnt vmcnt(8)" ::: "memory");
    else     asm volatile("s_waitcnt vmcnt(4)" ::: "memory");
  } else {
    if (isA) asm volatile("s_waitcnt vmcnt(4)" ::: "memory");
    else     asm volatile("s_waitcnt vmcnt(2)" ::: "memory");
  }
  __builtin_amdgcn_s_barrier();

  for (int t = 0; t < NT; ++t) {
    const int b = t % 3;
    // issue tile t+2 (stays in flight across the barrier below)
    if (t + 2 < NT) {
      const int k2 = (t + 2) * 32;
      const int b2 = (t + 2) % 3;
      _Float16* d = (isA ? &tA[limb][b2][0] : &tB[limb][b2][0]) + dstoff * 512;
      for (int i = 0; i < nch; ++i)
        gload16(sbase + (long)(16 * i) * sld + k2, d + i * 512);
    }

    half8 bh_[2], bl_[2];
#pragma unroll
    for (int ni = 0; ni < 2; ++ni) {
      bh_[ni] = *(const half8*)&tB[0][b][(wc + ni * 16 + fr) * 32 + fqs];
      if constexpr (PROD == 3)
        bl_[ni] = *(const half8*)&tB[1][b][(wc + ni * 16 + fr) * 32 + fqs];
    }
    half8 ah_[4], al_[4];
#pragma unroll
    for (int mi = 0; mi < 4; ++mi) {
      ah_[mi] = *(const half8*)&tA[0][b][(wr + mi * 16 + fr) * 32 + fqs];
      if constexpr (PROD == 3)
        al_[mi] = *(const half8*)&tA[1][b][(wr + mi * 16 + fr) * 32 + fqs];
    }
#pragma unroll
    for (int mi = 0; mi < 4; ++mi)
#pragma unroll
      for (int ni = 0; ni < 2; ++ni)
        acc0[mi][ni] = __builtin_amdgcn_mfma_f32_16x16x32_f16(ah_[mi], bh_[ni], acc0[mi][ni], 0, 0, 0);
    if constexpr (PROD == 3) {
#pragma unroll
      for (int mi = 0; mi < 4; ++mi)
#pragma unroll
        for (int ni = 0; ni < 2; ++ni)
          acc1[mi][ni] = __builtin_amdgcn_mfma_f32_16x16x32_f16(ah_[mi], bl_[ni], acc1[mi][ni], 0, 0, 0);
#pragma unroll
      for (int mi = 0; mi < 4; ++mi)
#pragma unroll
        for (int ni = 0; ni < 2; ++ni)
          acc1[mi][ni] = __builtin_amdgcn_mfma_f32_16x16x32_f16(al_[mi], bh_[ni], acc1[mi][ni], 0, 0, 0);
    }

    if (t + 1 < NT) {
      if (t + 2 < NT) {
        if constexpr (PROD == 3) {
          if (isA) asm volatile("s_waitcnt vmcnt(8)" ::: "memory");
          else     asm volatile("s_waitcnt vmcnt(4)" ::: "memory");
        } else {
          if (isA) asm volatile("s_waitcnt vmcnt(4)" ::: "memory");
          else     asm volatile("s_waitcnt vmcnt(2)" ::: "memory");
        }
      } else {
        asm volatile("s_waitcnt vmcnt(0)" ::: "memory");
      }
      __builtin_amdgcn_s_barrier();
    }
  }

#pragma unroll
  for (int mi = 0; mi < 4; ++mi) {
#pragma unroll
    for (int ni = 0; ni < 2; ++ni) {
      int gcol = bcol + wc + ni * 16 + fr;
      float bv = 0.0f;
      if constexpr (HAS_BIAS) bv = bias[(long)z1 * sBias + gcol];
#pragma unroll
      for (int v = 0; v < 4; ++v) {
        int grow = brow + wr + mi * 16 + (lane >> 4) * 4 + v;
        float val = acc0[mi][ni][v] + bv;
        if constexpr (PROD == 3) val += acc1[mi][ni][v] * 0.000244140625f;
        if constexpr (EPI == 0) {
          Cf[coff + (long)grow * ldcf + gcol] = val;
        } else if constexpr (EPI == 1) {
          _Float16 hh = (_Float16)val;
          _Float16 ll = (_Float16)((val - (float)hh) * 4096.0f);
          long ci = coff + (long)grow * ldch + gcol;
          Ch[ci] = hh; Cl[ci] = ll;
        } else if constexpr (EPI == 3) {
          Ch[coff + (long)grow * ldch + gcol] = (_Float16)val;
        } else {
          if (bcol < 2048) {       // uniform per block
            _Float16 hh = (_Float16)val;
            _Float16 ll = (_Float16)((val - (float)hh) * 4096.0f);
            long ci = (long)grow * ldch + gcol;
            Ch[ci] = hh; Cl[ci] = ll;
          } else {
            Cf[(long)grow * ldcf + (gcol - 2048)] = val;
          }
        }
      }
    }
  }
}

// ---------------------------------------------------------------------------
// bf16 MFMA GEMM (experts): 128x128 tile, K-step 32, 3-STAGE counted-vmcnt
// pipeline (T4), bank-swizzled LDS, 48KB -> 3 blocks/CU.  Z = expert index.
// ---------------------------------------------------------------------------
template<bool OUT_BF16, bool HAS_BIAS>
__global__ __launch_bounds__(256) void bgemm16(
    const bf16_t* __restrict__ A, const bf16_t* __restrict__ B,
    void* __restrict__ Cout, const float* __restrict__ bias,
    int K, long lda, long ldb, long ldc,
    long sA1, long sB1, long sC1, long sBias)
{
  __shared__ bf16_t tiles[2][3][128 * 32];
  const int z = blockIdx.z;
  const long coff = (long)z * sC1;
  const int brow = blockIdx.y * 128, bcol = blockIdx.x * 128;
  const int tid = threadIdx.x, lane = tid & 63, wid = tid >> 6;
  const int wr = (wid >> 1) * 64, wc = (wid & 1) * 64;
  const int fr = lane & 15;
  const int fqs = (((lane >> 4) ^ ((fr >> 1) & 3)) * 8);

  const bf16_t* src0 = (wid < 2) ? (A + (long)z * sA1) : (B + (long)z * sB1);
  const long ld = (wid < 2) ? lda : ldb;
  const int  rb = ((wid < 2) ? brow : bcol) + 64 * (wid & 1) + (lane >> 2);
  const bf16_t* srcbase = src0 + (long)rb * ld + SRC_SWZ(lane) * 8;
  const int tsel = wid >> 1, halfsel = wid & 1;

  f32x4 acc[4][4];
#pragma unroll
  for (int mi = 0; mi < 4; ++mi)
#pragma unroll
    for (int ni = 0; ni < 4; ++ni)
      acc[mi][ni] = f32x4{0.0f, 0.0f, 0.0f, 0.0f};

  const int NT = K >> 5;

  // prologue: tiles 0,1 issued; drain tile 0 (leave 4 of tile 1 in flight)
#pragma unroll
  for (int i = 0; i < 4; ++i)
    gload16(srcbase + (long)(16 * i) * ld, &tiles[tsel][0][(4 * halfsel + i) * 512]);
#pragma unroll
  for (int i = 0; i < 4; ++i)
    gload16(srcbase + (long)(16 * i) * ld + 32, &tiles[tsel][1][(4 * halfsel + i) * 512]);
  asm volatile("s_waitcnt vmcnt(4)" ::: "memory");
  __builtin_amdgcn_s_barrier();

  for (int t = 0; t < NT; ++t) {
    const int b = t % 3;
    if (t + 2 < NT) {
      const int k2 = (t + 2) * 32;
      const int b2 = (t + 2) % 3;
#pragma unroll
      for (int i = 0; i < 4; ++i)
        gload16(srcbase + (long)(16 * i) * ld + k2, &tiles[tsel][b2][(4 * halfsel + i) * 512]);
    }

    bf16x8 af[4], bfv[4];
#pragma unroll
    for (int i = 0; i < 4; ++i) {
      af[i]  = *(const bf16x8*)&tiles[0][b][(wr + i * 16 + fr) * 32 + fqs];
      bfv[i] = *(const bf16x8*)&tiles[1][b][(wc + i * 16 + fr) * 32 + fqs];
    }
#pragma unroll
    for (int mi = 0; mi < 4; ++mi)
#pragma unroll
      for (int ni = 0; ni < 4; ++ni)
        acc[mi][ni] = __builtin_amdgcn_mfma_f32_16x16x32_bf16(af[mi], bfv[ni], acc[mi][ni], 0, 0, 0);

    if (t + 1 < NT) {
      if (t + 2 < NT) asm volatile("s_waitcnt vmcnt(4)" ::: "memory");
      else            asm volatile("s_waitcnt vmcnt(0)" ::: "memory");
      __builtin_amdgcn_s_barrier();
    }
  }

#pragma unroll
  for (int mi = 0; mi < 4; ++mi) {
#pragma unroll
    for (int ni = 0; ni < 4; ++ni) {
      int gcol = bcol + wc + ni * 16 + fr;
      float bv = 0.0f;
      if constexpr (HAS_BIAS) bv = bias[(long)z * sBias + gcol];
#pragma unroll
      for (int v = 0; v < 4; ++v) {
        int grow = brow + wr + mi * 16 + (lane >> 4) * 4 + v;
        float val = acc[mi][ni][v] + bv;
        long ci = coff + (long)grow * ldc + gcol;
        if constexpr (OUT_BF16) ((bf16_t*)Cout)[ci] = (bf16_t)val;
        else                    ((float*)Cout)[ci]  = val;
      }
    }
  }
}

// ---------------------------------------------------------------------------
// 32x32 tiled transpose: dst[c][r] = (TOUT)src[r][c]; z-batched.
// ---------------------------------------------------------------------------
template<typename TOUT>
__global__ __launch_bounds__(256) void transpose_f32(
    const float* __restrict__ src, TOUT* __restrict__ dst,
    long ld_src, long ld_dst, int Z2,
    long ss1, long ss2, long sd1, long sd2)
{
  __shared__ float t[32][33];
  const int z = blockIdx.z, z1 = z / Z2, z2 = z - z1 * Z2;
  src += (long)z1 * ss1 + (long)z2 * ss2;
  dst += (long)z1 * sd1 + (long)z2 * sd2;
  const int c0 = blockIdx.x * 32, r0 = blockIdx.y * 32;
  const int tx = threadIdx.x & 31, ty = threadIdx.x >> 5;
#pragma unroll
  for (int i = 0; i < 4; ++i)
    t[ty + i * 8][tx] = src[(long)(r0 + ty + i * 8) * ld_src + c0 + tx];
  __syncthreads();
#pragma unroll
  for (int i = 0; i < 4; ++i)
    dst[(long)(c0 + ty + i * 8) * ld_dst + r0 + tx] = (TOUT)t[tx][ty + i * 8];
}

// ---------------------------------------------------------------------------
// transpose + split: dsth/dstl[c][r] = f16 limbs of src[r][c]; z-batched.
// ---------------------------------------------------------------------------
__global__ __launch_bounds__(256) void transpose_split(
    const float* __restrict__ src, _Float16* __restrict__ dh, _Float16* __restrict__ dl,
    long ld_src, long ld_dst, int Z2,
    long ss1, long ss2, long sd1, long sd2)
{
  __shared__ float t[32][33];
  const int z = blockIdx.z, z1 = z / Z2, z2 = z - z1 * Z2;
  src += (long)z1 * ss1 + (long)z2 * ss2;
  dh  += (long)z1 * sd1 + (long)z2 * sd2;
  dl  += (long)z1 * sd1 + (long)z2 * sd2;
  const int c0 = blockIdx.x * 32, r0 = blockIdx.y * 32;
  const int tx = threadIdx.x & 31, ty = threadIdx.x >> 5;
#pragma unroll
  for (int i = 0; i < 4; ++i)
    t[ty + i * 8][tx] = src[(long)(r0 + ty + i * 8) * ld_src + c0 + tx];
  __syncthreads();
#pragma unroll
  for (int i = 0; i < 4; ++i) {
    float v = t[tx][ty + i * 8];
    _Float16 h = (_Float16)v;
    _Float16 l = (_Float16)((v - (float)h) * 4096.0f);
    long idx = (long)(c0 + ty + i * 8) * ld_dst + r0 + tx;
    dh[idx] = h;
    dl[idx] = l;
  }
}

// ---------------------------------------------------------------------------
// In-place f16 row softmax (len 1024): scores row -> P row (both f16).
// ---------------------------------------------------------------------------
__global__ __launch_bounds__(256) void softmax16(
    _Float16* __restrict__ Sm, float scale)
{
  __shared__ float red[4];
  const long row = blockIdx.x;
  half4* p = (half4*)(Sm + row * 1024);
  const int tid = threadIdx.x;
  half4 hv = p[tid];
  float v0 = (float)hv.x, v1 = (float)hv.y, v2 = (float)hv.z, v3 = (float)hv.w;
  float m = fmaxf(fmaxf(v0, v1), fmaxf(v2, v3));
#pragma unroll
  for (int o = 32; o; o >>= 1) m = fmaxf(m, __shfl_xor(m, o, 64));
  if ((tid & 63) == 0) red[tid >> 6] = m;
  __syncthreads();
  m = fmaxf(fmaxf(red[0], red[1]), fmaxf(red[2], red[3]));
  __syncthreads();
  float e0 = __expf((v0 - m) * scale);
  float e1 = __expf((v1 - m) * scale);
  float e2 = __expf((v2 - m) * scale);
  float e3 = __expf((v3 - m) * scale);
  float s = e0 + e1 + e2 + e3;
#pragma unroll
  for (int o = 32; o; o >>= 1) s += __shfl_xor(s, o, 64);
  if ((tid & 63) == 0) red[tid >> 6] = s;
  __syncthreads();
  s = red[0] + red[1] + red[2] + red[3];
  float inv = 1.0f / s;
  half4 w;
  w.x = (_Float16)(e0 * inv); w.y = (_Float16)(e1 * inv);
  w.z = (_Float16)(e2 * inv); w.w = (_Float16)(e3 * inv);
  p[tid] = w;
}

// ---------------------------------------------------------------------------
// Row softmax (len 1024) fp32 IN PLACE -> packed f16 limb pair (patch path).
// ---------------------------------------------------------------------------
template<bool WRITE_LO>
__global__ __launch_bounds__(256) void softmax_pack(
    float* __restrict__ Sm, float scale)
{
  __shared__ float red[4];
  const long row = blockIdx.x;
  const float4* p = (const float4*)(Sm + row * 1024);
  const int tid = threadIdx.x;
  float4 v = p[tid];
  float m = fmaxf(fmaxf(v.x, v.y), fmaxf(v.z, v.w));
#pragma unroll
  for (int o = 32; o; o >>= 1) m = fmaxf(m, __shfl_xor(m, o, 64));
  if ((tid & 63) == 0) red[tid >> 6] = m;
  __syncthreads();
  m = fmaxf(fmaxf(red[0], red[1]), fmaxf(red[2], red[3]));
  __syncthreads();
  float e0 = __expf((v.x - m) * scale);
  float e1 = __expf((v.y - m) * scale);
  float e2 = __expf((v.z - m) * scale);
  float e3 = __expf((v.w - m) * scale);
  float s = e0 + e1 + e2 + e3;
#pragma unroll
  for (int o = 32; o; o >>= 1) s += __shfl_xor(s, o, 64);
  if ((tid & 63) == 0) red[tid >> 6] = s;
  __syncthreads();
  s = red[0] + red[1] + red[2] + red[3];
  float inv = 1.0f / s;
  float p0 = e0 * inv, p1 = e1 * inv, p2 = e2 * inv, p3 = e3 * inv;
  half4 h;
  h.x = (_Float16)p0; h.y = (_Float16)p1; h.z = (_Float16)p2; h.w = (_Float16)p3;
  _Float16* base = (_Float16*)Sm + row * 2048;
  ((half4*)base)[tid] = h;
  if constexpr (WRITE_LO) {
    half4 l;
    l.x = (_Float16)((p0 - (float)h.x) * 4096.0f);
    l.y = (_Float16)((p1 - (float)h.y) * 4096.0f);
    l.z = (_Float16)((p2 - (float)h.z) * 4096.0f);
    l.w = (_Float16)((p3 - (float)h.w) * 4096.0f);
    ((half4*)(base + 1024))[tid] = l;
  }
}

// ---------------------------------------------------------------------------
// Fused: y1 = LN(x + attn) -> bf16 y1b; gate logits, argmax idx, gval;
// borderline tokens (gap < TAU) appended to per-sequence lists (cap 128).
// ---------------------------------------------------------------------------
__global__ __launch_bounds__(256) void add_ln_gate(
    const float* __restrict__ x, const float* __restrict__ attn,
    const float* __restrict__ g, const float* __restrict__ be,
    const float* __restrict__ wg, bf16_t* __restrict__ yb,
    int* __restrict__ idx, float* __restrict__ gval,
    int* __restrict__ bcnt16, int* __restrict__ blist16)
{
  __shared__ float red[4];
  __shared__ float lred[4][8];
  const long s = blockIdx.x;
  const int tid = threadIdx.x;
  const int lane = tid & 63, w = tid >> 6;
  float4 va = ((const float4*)(x + s * 1024))[tid];
  float4 vb = ((const float4*)(attn + s * 1024))[tid];
  float v0 = va.x + vb.x, v1 = va.y + vb.y, v2 = va.z + vb.z, v3 = va.w + vb.w;
  float sum = v0 + v1 + v2 + v3;
#pragma unroll
  for (int o = 32; o; o >>= 1) sum += __shfl_xor(sum, o, 64);
  if (lane == 0) red[w] = sum;
  __syncthreads();
  float mu = (red[0] + red[1] + red[2] + red[3]) * (1.0f / 1024.0f);
  __syncthreads();
  float d0 = v0 - mu, d1 = v1 - mu, d2 = v2 - mu, d3 = v3 - mu;
  float ss = d0 * d0 + d1 * d1 + d2 * d2 + d3 * d3;
#pragma unroll
  for (int o = 32; o; o >>= 1) ss += __shfl_xor(ss, o, 64);
  if (lane == 0) red[w] = ss;
  __syncthreads();
  float var = (red[0] + red[1] + red[2] + red[3]) * (1.0f / 1024.0f);
  float rstd = rsqrtf(var + 1e-5f);
  float4 vg  = ((const float4*)g)[tid];
  float4 vbe = ((const float4*)be)[tid];
  float y0 = d0 * rstd * vg.x + vbe.x;
  float y1v = d1 * rstd * vg.y + vbe.y;
  float y2v = d2 * rstd * vg.z + vbe.z;
  float y3 = d3 * rstd * vg.w + vbe.w;
  bf16x4 ov = { (bf16_t)y0, (bf16_t)y1v, (bf16_t)y2v, (bf16_t)y3 };
  *(bf16x4*)(yb + s * 1024 + tid * 4) = ov;
  float lg[8];
  const float* w0 = wg + (long)(tid * 4) * 8;
#pragma unroll
  for (int e = 0; e < 8; ++e)
    lg[e] = y0 * w0[e] + y1v * w0[8 + e] + y2v * w0[16 + e] + y3 * w0[24 + e];
#pragma unroll
  for (int e = 0; e < 8; ++e) {
#pragma unroll
    for (int o = 32; o; o >>= 1) lg[e] += __shfl_xor(lg[e], o, 64);
  }
  if (lane == 0) {
#pragma unroll
    for (int e = 0; e < 8; ++e) lred[w][e] = lg[e];
  }
  __syncthreads();
  if (tid == 0) {
    float Lg[8];
#pragma unroll
    for (int e = 0; e < 8; ++e)
      Lg[e] = lred[0][e] + lred[1][e] + lred[2][e] + lred[3][e];
    float best = Lg[0], second = -1e30f; int bi = 0;
#pragma unroll
    for (int e = 1; e < 8; ++e) {
      if (Lg[e] > best) { second = best; best = Lg[e]; bi = e; }
      else if (Lg[e] > second) second = Lg[e];
    }
    float sm = 0.0f;
#pragma unroll
    for (int e = 0; e < 8; ++e) sm += __expf(Lg[e] - best);
    idx[s] = bi;
    gval[s] = 1.0f / sm;
    if (best - second < TAU_) {
      int n = (int)(s & 15);
      int p = atomicAdd(&bcnt16[n], 1);
      if (p < 128) blist16[n * 128 + p] = (int)s;
    }
  }
}

// ---------------------------------------------------------------------------
__global__ void zero16(int* __restrict__ p)
{
  if (threadIdx.x < 16) p[threadIdx.x] = 0;
}

// ---------------------------------------------------------------------------
// Gather borderline Q rows (limbs) into padded [16*128][1024]; pad rows zero.
// ---------------------------------------------------------------------------
__global__ __launch_bounds__(64) void qp_gather(
    const int* __restrict__ bcnt16, const int* __restrict__ blist16,
    const _Float16* __restrict__ QKh, const _Float16* __restrict__ QKl,
    _Float16* __restrict__ Qph, _Float16* __restrict__ Qpl)
{
  const int b = blockIdx.x;
  const int n = b >> 7, p = b & 127;
  const int t = threadIdx.x;
  half8* dh = (half8*)(Qph + (long)b * 1024);
  half8* dl = (half8*)(Qpl + (long)b * 1024);
  int cnt = bcnt16[n]; if (cnt > 128) cnt = 128;
  if (p < cnt) {
    long srow = (long)blist16[b] * 2048;
    const half8* sh = (const half8*)(QKh + srow);
    const half8* sl = (const half8*)(QKl + srow);
    dh[t * 2]     = sh[t * 2];
    dh[t * 2 + 1] = sh[t * 2 + 1];
    dl[t * 2]     = sl[t * 2];
    dl[t * 2 + 1] = sl[t * 2 + 1];
  } else {
    half8 z;
#pragma unroll
    for (int i = 0; i < 8; ++i) z[i] = (_Float16)0.0f;
    dh[t * 2] = z; dh[t * 2 + 1] = z;
    dl[t * 2] = z; dl[t * 2 + 1] = z;
  }
}

// ---------------------------------------------------------------------------
// Final fix: exact y1 row + logits from exact attn_p; overwrite idx/gval.
// ---------------------------------------------------------------------------
__global__ __launch_bounds__(256) void gate_fix(
    const int* __restrict__ bcnt16, const int* __restrict__ blist16,
    const float* __restrict__ attn_p, const float* __restrict__ x,
    const float* __restrict__ g, const float* __restrict__ be,
    const float* __restrict__ wg,
    int* __restrict__ idx, float* __restrict__ gval)
{
  const int b = blockIdx.x;
  const int n = b >> 7, p = b & 127;
  int cnt = bcnt16[n]; if (cnt > 128) cnt = 128;
  if (p >= cnt) return;
  const long s = blist16[b];
  __shared__ float red[4];
  __shared__ float lred[4][8];
  const int tid = threadIdx.x;
  const int lane = tid & 63, w = tid >> 6;
  float4 va = ((const float4*)(x + s * 1024))[tid];
  float4 vb = ((const float4*)(attn_p + (long)b * 1024))[tid];
  float v0 = va.x + vb.x, v1 = va.y + vb.y, v2 = va.z + vb.z, v3 = va.w + vb.w;
  float sum = v0 + v1 + v2 + v3;
#pragma unroll
  for (int o = 32; o; o >>= 1) sum += __shfl_xor(sum, o, 64);
  if (lane == 0) red[w] = sum;
  __syncthreads();
  float mu = (red[0] + red[1] + red[2] + red[3]) * (1.0f / 1024.0f);
  __syncthreads();
  float d0 = v0 - mu, d1 = v1 - mu, d2 = v2 - mu, d3 = v3 - mu;
  float ss = d0 * d0 + d1 * d1 + d2 * d2 + d3 * d3;
#pragma unroll
  for (int o = 32; o; o >>= 1) ss += __shfl_xor(ss, o, 64);
  if (lane == 0) red[w] = ss;
  __syncthreads();
  float var = (red[0] + red[1] + red[2] + red[3]) * (1.0f / 1024.0f);
  float rstd = rsqrtf(var + 1e-5f);
  float4 vg  = ((const float4*)g)[tid];
  float4 vbe = ((const float4*)be)[tid];
  float y0 = d0 * rstd * vg.x + vbe.x;
  float y1v = d1 * rstd * vg.y + vbe.y;
  float y2v = d2 * rstd * vg.z + vbe.z;
  float y3 = d3 * rstd * vg.w + vbe.w;
  float lg[8];
  const float* w0 = wg + (long)(tid * 4) * 8;
#pragma unroll
  for (int e = 0; e < 8; ++e)
    lg[e] = y0 * w0[e] + y1v * w0[8 + e] + y2v * w0[16 + e] + y3 * w0[24 + e];
#pragma unroll
  for (int e = 0; e < 8; ++e) {
#pragma unroll
    for (int o = 32; o; o >>= 1) lg[e] += __shfl_xor(lg[e], o, 64);
  }
  if (lane == 0) {
#pragma unroll
    for (int e = 0; e < 8; ++e) lred[w][e] = lg[e];
  }
  __syncthreads();
  if (tid == 0) {
    float Lg[8];
#pragma unroll
    for (int e = 0; e < 8; ++e)
      Lg[e] = lred[0][e] + lred[1][e] + lred[2][e] + lred[3][e];
    float best = Lg[0]; int bi = 0;
#pragma unroll
    for (int e = 1; e < 8; ++e) { if (Lg[e] > best) { best = Lg[e]; bi = e; } }
    float sm = 0.0f;
#pragma unroll
    for (int e = 0; e < 8; ++e) sm += __expf(Lg[e] - best);
    idx[s] = bi;
    gval[s] = 1.0f / sm;
  }
}

// ---------------------------------------------------------------------------
// out = LN(y1b + (keep ? gval * ymoe[slot] : 0); g, be)   [bf16 inputs]
// ---------------------------------------------------------------------------
__global__ __launch_bounds__(256) void combine_ln(
    const bf16_t* __restrict__ y1b, const bf16_t* __restrict__ ymoe,
    const int* __restrict__ slot, const float* __restrict__ gval,
    const float* __restrict__ g, const float* __restrict__ be,
    float* __restrict__ out)
{
  __shared__ float red[4];
  const long s = blockIdx.x;
  const int tid = threadIdx.x;
  const int lane = tid & 63, w = tid >> 6;
  int sl = slot[s];
  bool keep = sl < ESLOTS_;
  float gv = keep ? gval[s] : 0.0f;
  long mrow = keep ? (long)sl * 1024 : 0;
  bf16x4 ya = *(const bf16x4*)(y1b + s * 1024 + tid * 4);
  bf16x4 ym = *(const bf16x4*)(ymoe + mrow + tid * 4);
  float v0 = (float)ya[0] + gv * (float)ym[0];
  float v1 = (float)ya[1] + gv * (float)ym[1];
  float v2 = (float)ya[2] + gv * (float)ym[2];
  float v3 = (float)ya[3] + gv * (float)ym[3];
  float sum = v0 + v1 + v2 + v3;
#pragma unroll
  for (int o = 32; o; o >>= 1) sum += __shfl_xor(sum, o, 64);
  if (lane == 0) red[w] = sum;
  __syncthreads();
  float mu = (red[0] + red[1] + red[2] + red[3]) * (1.0f / 1024.0f);
  __syncthreads();
  float d0 = v0 - mu, d1 = v1 - mu, d2 = v2 - mu, d3 = v3 - mu;
  float ss = d0 * d0 + d1 * d1 + d2 * d2 + d3 * d3;
#pragma unroll
  for (int o = 32; o; o >>= 1) ss += __shfl_xor(ss, o, 64);
  if (lane == 0) red[w] = ss;
  __syncthreads();
  float var = (red[0] + red[1] + red[2] + red[3]) * (1.0f / 1024.0f);
  float rstd = rsqrtf(var + 1e-5f);
  float4 vg  = ((const float4*)g)[tid];
  float4 vbe = ((const float4*)be)[tid];
  float4 ov = {d0 * rstd * vg.x + vbe.x, d1 * rstd * vg.y + vbe.y,
               d2 * rstd * vg.z + vbe.z, d3 * rstd * vg.w + vbe.w};
  ((float4*)(out + s * 1024))[tid] = ov;
}

// ---------------------------------------------------------------------------
// Routing scan (single block, 1024 threads, 16 tokens each).
// ---------------------------------------------------------------------------
__global__ __launch_bounds__(1024) void route_scan(
    const int* __restrict__ idx, int* __restrict__ slot, int* __restrict__ tfs)
{
  __shared__ int c_lds[8][1024];
  const int tid = threadIdx.x;
  const int lane = tid & 63, wid = tid >> 6;

  for (int j = tid; j < ESLOTS_; j += 1024) tfs[j] = -1;

  int myc[8] = {0, 0, 0, 0, 0, 0, 0, 0};
  for (int j = 0; j < 16; ++j) {
    int e = idx[tid * 16 + j];
    myc[e]++;
  }
#pragma unroll
  for (int e = 0; e < 8; ++e) c_lds[e][tid] = myc[e];
  __syncthreads();

  if (wid < 8) {
    int carry = 0;
    for (int cb = 0; cb < 1024; cb += 64) {
      int v = c_lds[wid][cb + lane];
#pragma unroll
      for (int o = 1; o < 64; o <<= 1) {
        int t = __shfl_up(v, o, 64);
        if (lane >= o) v += t;
      }
      v += carry;
      c_lds[wid][cb + lane] = v;
      carry = __shfl(v, 63, 64);
    }
  }
  __syncthreads();

  int run[8] = {0, 0, 0, 0, 0, 0, 0, 0};
  for (int j = 0; j < 16; ++j) {
    int s = tid * 16 + j;
    int e = idx[s];
    int excl = c_lds[e][tid] - myc[e];
    int loc = excl + run[e];
    run[e]++;
    int sl = (loc < CAP_) ? e * CAP_ + loc : ESLOTS_;
    slot[s] = sl;
    if (sl < ESLOTS_) tfs[sl] = s;
  }
}

// ---------------------------------------------------------------------------
// Gather dispatch rows (bf16): disp[slot] = y1b[token] or zeros.
// ---------------------------------------------------------------------------
__global__ void dispatch_rows(
    const int* __restrict__ tfs, const bf16_t* __restrict__ y1b,
    bf16_t* __restrict__ disp)
{
  const int row = blockIdx.x;
  const int t = tfs[row];
  bf16x8* d = (bf16x8*)(disp + (long)row * 1024);
  if (t >= 0) {
    const bf16x8* sp = (const bf16x8*)(y1b + (long)t * 1024);
    d[threadIdx.x] = sp[threadIdx.x];
  } else {
    bf16x8 zv;
#pragma unroll
    for (int i = 0; i < 8; ++i) zv[i] = (bf16_t)0.0f;
    d[threadIdx.x] = zv;
  }
}

// ---------------------------------------------------------------------------
__global__ void fill_val(float* __restrict__ p, float v, long n)
{
  long i = (long)blockIdx.x * blockDim.x + threadIdx.x;
  long stride = (long)gridDim.x * blockDim.x;
  for (; i < n; i += stride) p[i] = v;
}

// ---------------------------------------------------------------------------
extern "C" void kernel_launch(void* const* d_in, const int* in_sizes, int n_in,
                              void* d_out, int out_size, void* d_ws, size_t ws_size,
                              hipStream_t stream)
{
  const float* x    = (const float*)d_in[0];
  const float* Wqkv = (const float*)d_in[1];
  const float* bqkv = (const float*)d_in[2];
  const float* Wo   = (const float*)d_in[3];
  const float* bo   = (const float*)d_in[4];
  const float* g1   = (const float*)d_in[5];
  const float* b1n  = (const float*)d_in[6];
  const float* g2   = (const float*)d_in[7];
  const float* b2n  = (const float*)d_in[8];
  const float* wg   = (const float*)d_in[9];
  const float* w1   = (const float*)d_in[10];
  const float* b1e  = (const float*)d_in[11];
  const float* w2   = (const float*)d_in[12];
  const float* b2e  = (const float*)d_in[13];
  float* out = (float*)d_out;

  const size_t MB = 1ull << 20;
  const size_t REQUIRED = 384 * MB;
  if (ws_size < REQUIRED) {
    fill_val<<<2048, 256, 0, stream>>>(out, (float)(ws_size >> 20), (long)out_size);
    return;
  }

  char* ws = (char*)d_ws;
  // Region map v4 (audited) — same as R14/R15:
  _Float16* Xh   = (_Float16*)(ws + 0);
  _Float16* Xl   = (_Float16*)(ws + 32 * MB);
  _Float16* Wqh  = (_Float16*)(ws + 64 * MB);
  _Float16* Wql  = (_Float16*)(ws + 70 * MB);
  _Float16* scores16 = (_Float16*)(ws + 0);
  _Float16* Woh  = (_Float16*)(ws + 64 * MB);
  _Float16* Wol  = (_Float16*)(ws + 66 * MB);
  _Float16* QKh  = (_Float16*)(ws + 80 * MB);
  _Float16* QKl  = (_Float16*)(ws + 144 * MB);
  float*    Vf32 = (float*)(ws + 208 * MB);
  _Float16* oh   = (_Float16*)(ws + 208 * MB);
  _Float16* vTh  = (_Float16*)(ws + 272 * MB);
  _Float16* vTl  = (_Float16*)(ws + 304 * MB);
  float*    attn = (float*)(ws + 0);
  bf16_t*   y1b  = (bf16_t*)(ws + 208 * MB);
  float*    scp   = (float*)(ws + 0);             // 32MB patch scores
  _Float16* Qph   = (_Float16*)(ws + 32 * MB);
  _Float16* Qpl   = (_Float16*)(ws + 36 * MB);
  _Float16* o_ph  = (_Float16*)(ws + 40 * MB);
  _Float16* o_pl  = (_Float16*)(ws + 44 * MB);
  float*    attnp = (float*)(ws + 48 * MB);
  int*      idx  = (int*)(ws + 336 * MB);
  int*      slot = idx + S_;
  float*    gval = (float*)(slot + S_);
  int*      tfs  = (int*)(gval + S_);
  int*      bcnt16  = tfs + S_;
  int*      blist16 = bcnt16 + 16;
  bf16_t*   disp = (bf16_t*)(ws + 272 * MB);
  bf16_t*   W1t  = (bf16_t*)(ws + 0);
  bf16_t*   W2t  = (bf16_t*)(ws + 0);
  bf16_t*   h    = (bf16_t*)(ws + 80 * MB);
  bf16_t*   ymoe = (bf16_t*)(ws + 304 * MB);

  // 0. zero borderline counters early
  zero16<<<1, 64, 0, stream>>>(bcnt16);

  // 1. pre-split x and Wqkv to f16 limbs
  split2<<<4096, 256, 0, stream>>>(x, Xh, Xl, (long)S_ * D_ / 4);
  split2<<<2048, 256, 0, stream>>>(Wqkv, Wqh, Wql, (long)3 * D_ * D_ / 4);

  // 2. qkv GEMM (3-product, 3-stage pipeline): Q,K -> limb pairs; V -> fp32
  hgemm3s<2, true, 3><<<dim3(48, 128, 1), 256, 0, stream>>>(
      Xh, Xl, Wqh, Wql, Vf32, QKh, QKl, bqkv,
      D_, D_, D_, D_, 2 * D_,
      1, 0, 0, 0, 0, 0, 0, 0);

  // 3. split Wo
  split2<<<1024, 256, 0, stream>>>(Wo, Woh, Wol, (long)D_ * D_ / 4);

  // 4. vT limbs [n,h][HD][L] from Vf32 [S][D]
  transpose_split<<<dim3(HD_ / 32, L_ / 32, 64), 256, 0, stream>>>(
      Vf32, vTh, vTl, (long)N_ * D_, L_,
      H_, D_, HD_, (long)H_ * HD_ * L_, (long)HD_ * L_);

  // 5. attention main path (1-product f16, 3-stage pipeline), 2 groups of 8
  for (int g = 0; g < 2; ++g) {
    const long qko = (long)g * 8 * 2048;
    hgemm3s<3, false, 1><<<dim3(16, 8, 32), 256, 0, stream>>>(
        QKh + qko, QKl + qko, QKh + qko + 1024, QKl + qko + 1024,
        nullptr, scores16, nullptr, nullptr,
        HD_, (long)N_ * 2048, (long)N_ * 2048, 0, L_,
        H_, 2048, 256, 2048, 256, (long)H_ * L_ * L_, (long)L_ * L_, 0);
    softmax16<<<8 * H_ * L_, 256, 0, stream>>>(scores16, 0.0625f);
    hgemm3s<3, false, 1><<<dim3(4, 8, 32), 256, 0, stream>>>(
        scores16, nullptr,
        vTh + (long)g * 8 * H_ * HD_ * L_, vTl + (long)g * 8 * H_ * HD_ * L_,
        nullptr, oh + (long)g * 8 * D_, nullptr, nullptr,
        L_, L_, L_, 0, (long)N_ * D_,
        H_, (long)H_ * L_ * L_, (long)L_ * L_,
        (long)H_ * HD_ * L_, (long)HD_ * L_, D_, HD_, 0);
  }

  // 6. attn = o @ Wo^T + bo   (1-product, 3-stage)
  hgemm3s<0, true, 1><<<dim3(16, 128, 1), 256, 0, stream>>>(
      oh, nullptr, Woh, Wol, attn, nullptr, nullptr, bo,
      D_, D_, D_, D_, 0,
      1, 0, 0, 0, 0, 0, 0, 0);

  // 7. fused LN + gate + borderline detection (writes y1b bf16)
  add_ln_gate<<<S_, 256, 0, stream>>>(x, attn, g1, b1n, wg, y1b,
                                      idx, gval, bcnt16, blist16);

  // 8. exact-gate patch for borderline tokens (3-product grade, 3-stage)
  qp_gather<<<2048, 64, 0, stream>>>(bcnt16, blist16, QKh, QKl, Qph, Qpl);
  hgemm3s<0, false, 3><<<dim3(16, 1, 64), 256, 0, stream>>>(
      Qph, Qpl, QKh + 1024, QKl + 1024, scp, nullptr, nullptr, nullptr,
      HD_, 1024, (long)N_ * 2048, 1024, 0,
      4, (long)128 * 1024, 256, 2048, 256,
      (long)4 * 128 * 1024, (long)128 * 1024, 0);
  softmax_pack<true><<<64 * 128, 256, 0, stream>>>(scp, 0.0625f);
  hgemm3s<1, false, 3><<<dim3(4, 1, 64), 256, 0, stream>>>(
      (_Float16*)scp, (_Float16*)scp + 1024, vTh, vTl,
      nullptr, o_ph, o_pl, nullptr,
      L_, 2048, L_, 0, 1024,
      4, (long)4 * 128 * 2048, (long)128 * 2048,
      (long)H_ * HD_ * L_, (long)HD_ * L_,
      (long)128 * 1024, 256, 0);
  hgemm3s<0, true, 3><<<dim3(16, 16, 1), 256, 0, stream>>>(
      o_ph, o_pl, Woh, Wol, attnp, nullptr, nullptr, bo,
      D_, D_, D_, D_, 0,
      1, 0, 0, 0, 0, 0, 0, 0);
  gate_fix<<<2048, 256, 0, stream>>>(bcnt16, blist16, attnp, x,
                                     g1, b1n, wg, idx, gval);

  // 9. token-order routing scan + capacity drop
  route_scan<<<1, 1024, 0, stream>>>(idx, slot, tfs);

  // 10. gather dispatch rows (bf16)
  dispatch_rows<<<ESLOTS_, 128, 0, stream>>>(tfs, y1b, disp);

  // 11. W1t[e][FF][D] bf16 from w1 fp32 (patch scratch dead)
  transpose_f32<bf16_t><<<dim3(FF_ / 32, D_ / 32, E_), 256, 0, stream>>>(
      w1, W1t, FF_, D_, 1, (long)D_ * FF_, 0, (long)FF_ * D_, 0);

  // 12. h[e] = disp[e] @ w1[e] + b1[e]; 3-stage bgemm, grid (32,16,8)
  bgemm16<true, true><<<dim3(32, 16, 8), 256, 0, stream>>>(
      disp, W1t, h, b1e, D_, D_, D_, FF_,
      (long)CAP_ * D_, (long)FF_ * D_, (long)CAP_ * FF_, FF_);

  // 13. W2t[e][D][FF] bf16 from w2 fp32
  transpose_f32<bf16_t><<<dim3(D_ / 32, FF_ / 32, E_), 256, 0, stream>>>(
      w2, W2t, D_, FF_, 1, (long)FF_ * D_, 0, (long)D_ * FF_, 0);

  // 14. ymoe[e] (bf16) = h[e] @ w2[e] + b2[e]; grid (8,16,8)
  bgemm16<true, true><<<dim3(8, 16, 8), 256, 0, stream>>>(
      h, W2t, ymoe, b2e, FF_, FF_, FF_, D_,
      (long)CAP_ * FF_, (long)D_ * FF_, (long)CAP_ * D_, D_);

  // 15. out = LN(y1b + combine)
  combine_ln<<<S_, 256, 0, stream>>>(y1b, ymoe, slot, gval, g2, b2n, out);
}

// Round 17
// 1476.835 us; speedup vs baseline: 1.0183x; 1.0183x over previous
//
#include <hip/hip_runtime.h>
#include <hip/hip_bf16.h>

typedef __bf16 bf16_t;
typedef bf16_t bf16x4 __attribute__((ext_vector_type(4)));
typedef bf16_t bf16x8 __attribute__((ext_vector_type(8)));
typedef float  f32x4  __attribute__((ext_vector_type(4)));
typedef _Float16 half4 __attribute__((ext_vector_type(4)));
typedef _Float16 half8 __attribute__((ext_vector_type(8)));

// Problem constants
#define L_  1024
#define N_  16
#define S_  16384          // L*N tokens
#define D_  1024
#define H_  4
#define HD_ 256
#define E_  8
#define FF_ 4096
#define CAP_ 2048
#define ESLOTS_ (E_*CAP_)  // 16384
#define TAU_ 0.03f         // borderline gate-gap threshold

// ---------------------------------------------------------------------------
// async global->LDS, 16B per lane: dest = ldsbase + lane*16 (wave-uniform base)
// ---------------------------------------------------------------------------
__device__ __forceinline__ void gload16(const void* g, void* l) {
  __builtin_amdgcn_global_load_lds(
      (const __attribute__((address_space(1))) void*)g,
      (__attribute__((address_space(3))) void*)l,
      16, 0, 0);
}

// LDS bank swizzle (verified R10: conflicts -> 0). inverse-swizzled SOURCE +
// swizzled READ, LDS stays linear for global_load_lds.
#define SRC_SWZ(lane) (((lane) & 3) ^ (((lane) >> 3) & 3))

// ---------------------------------------------------------------------------
// split2: fp32 -> f16 two-limb (hi, lo*4096)
// ---------------------------------------------------------------------------
__global__ __launch_bounds__(256) void split2(
    const float* __restrict__ in, _Float16* __restrict__ oh,
    _Float16* __restrict__ ol, long n4)
{
  long i = (long)blockIdx.x * blockDim.x + threadIdx.x;
  long stride = (long)gridDim.x * blockDim.x;
  for (; i < n4; i += stride) {
    float4 v = ((const float4*)in)[i];
    half4 h, l;
    h.x = (_Float16)v.x; l.x = (_Float16)((v.x - (float)h.x) * 4096.0f);
    h.y = (_Float16)v.y; l.y = (_Float16)((v.y - (float)h.y) * 4096.0f);
    h.z = (_Float16)v.z; l.z = (_Float16)((v.z - (float)h.z) * 4096.0f);
    h.w = (_Float16)v.w; l.w = (_Float16)((v.w - (float)h.w) * 4096.0f);
    ((half4*)oh)[i] = h;
    ((half4*)ol)[i] = l;
  }
}

// ---------------------------------------------------------------------------
// MFMA GEMM on pre-split f16 limbs.
// PROD==3: C = Ah*Bh + (Ah*Bl + Al*Bh)/4096  (fp32-class; 2-phase dbuf loop,
//          byte-identical schedule to the R12/R15-passing kernel, 48KB LDS)
// PROD==1: C = Ah*Bh  (f16-class) with 3-STAGE COUNTED-VMCNT PIPELINE (T4,
//          R15-verified): triple-buffer LDS; iter t issues tile t+2, computes
//          tile t, drains only tile t+1 (vmcnt=nch), raw s_barrier.
// Block 128x64, K-step 32, 4 waves (2x2), per-wave 64x32, bank-swizzled LDS.
// EPI: 0 fp32 C; 1 limb-pair C; 2 qkv special; 3 f16-only.
// Row-block = blockIdx.Y, col-block = blockIdx.X (L2 locality, R13).
// ---------------------------------------------------------------------------
template<int EPI, bool HAS_BIAS, int PROD>
__global__ __launch_bounds__(256) void hgemm3s(
    const _Float16* __restrict__ Ah, const _Float16* __restrict__ Al,
    const _Float16* __restrict__ Bh, const _Float16* __restrict__ Bl,
    float* __restrict__ Cf, _Float16* __restrict__ Ch, _Float16* __restrict__ Cl,
    const float* __restrict__ bias,
    int K, long lda, long ldb, long ldcf, long ldch,
    int Z2, long sA1, long sA2, long sB1, long sB2, long sC1, long sC2, long sBias)
{
  constexpr int NL   = (PROD == 3) ? 2 : 1;
  constexpr int NBUF = (PROD == 3) ? 2 : 3;
  __shared__ _Float16 tA[NL][NBUF][128 * 32];
  __shared__ _Float16 tB[NL][NBUF][64 * 32];
  const int z  = blockIdx.z;
  const int z1 = z / Z2, z2 = z - z1 * Z2;
  const long aoff = (long)z1 * sA1 + (long)z2 * sA2;
  const long boff = (long)z1 * sB1 + (long)z2 * sB2;
  const long coff = (long)z1 * sC1 + (long)z2 * sC2;
  const int brow = blockIdx.y * 128, bcol = blockIdx.x * 64;
  const int tid = threadIdx.x, lane = tid & 63, wid = tid >> 6;
  const int wr = (wid >> 1) * 64, wc = (wid & 1) * 32;
  const int fr = lane & 15;
  const int fqs = (((lane >> 4) ^ ((fr >> 1) & 3)) * 8);

  // staging roles
  const bool isA = (wid < 2);
  int limb, dstoff, nch;
  const _Float16* ssrc;
  if constexpr (PROD == 3) {
    limb = wid & 1; nch = isA ? 8 : 4; dstoff = 0;
    ssrc = (wid == 0) ? Ah : (wid == 1) ? Al : (wid == 2) ? Bh : Bl;
  } else {
    limb = 0; nch = isA ? 4 : 2; dstoff = (wid & 1) * nch;
    ssrc = isA ? Ah : Bh;
  }
  const long sld = isA ? lda : ldb;
  const long soff = isA ? aoff : boff;
  int srow = (isA ? brow : bcol) + (lane >> 2);
  if constexpr (PROD == 1) srow += (wid & 1) * (isA ? 64 : 32);
  const _Float16* sbase = ssrc + soff + (long)srow * sld + SRC_SWZ(lane) * 8;

  f32x4 acc0[4][2], acc1[4][2];
#pragma unroll
  for (int mi = 0; mi < 4; ++mi)
#pragma unroll
    for (int ni = 0; ni < 2; ++ni) {
      acc0[mi][ni] = f32x4{0.f, 0.f, 0.f, 0.f};
      acc1[mi][ni] = f32x4{0.f, 0.f, 0.f, 0.f};
    }

  const int NT = K >> 5;

  if constexpr (PROD == 3) {
    // ---- 2-phase dbuf loop (verified R12/R15) ----
    {
      _Float16* d0 = (isA ? &tA[limb][0][0] : &tB[limb][0][0]) + dstoff * 512;
      for (int i = 0; i < nch; ++i)
        gload16(sbase + (long)(16 * i) * sld, d0 + i * 512);
    }
    __syncthreads();

    for (int t = 0; t < NT; ++t) {
      const int cur = t & 1;
      if (t + 1 < NT) {
        const int k1 = (t + 1) * 32;
        _Float16* d0 = (isA ? &tA[limb][cur ^ 1][0] : &tB[limb][cur ^ 1][0]) + dstoff * 512;
        for (int i = 0; i < nch; ++i)
          gload16(sbase + (long)(16 * i) * sld + k1, d0 + i * 512);
      }

      half8 bh_[2], bl_[2];
#pragma unroll
      for (int ni = 0; ni < 2; ++ni) {
        bh_[ni] = *(const half8*)&tB[0][cur][(wc + ni * 16 + fr) * 32 + fqs];
        bl_[ni] = *(const half8*)&tB[1][cur][(wc + ni * 16 + fr) * 32 + fqs];
      }
      half8 ah_[4], al_[4];
#pragma unroll
      for (int mi = 0; mi < 4; ++mi) {
        ah_[mi] = *(const half8*)&tA[0][cur][(wr + mi * 16 + fr) * 32 + fqs];
        al_[mi] = *(const half8*)&tA[1][cur][(wr + mi * 16 + fr) * 32 + fqs];
      }
#pragma unroll
      for (int mi = 0; mi < 4; ++mi)
#pragma unroll
        for (int ni = 0; ni < 2; ++ni)
          acc0[mi][ni] = __builtin_amdgcn_mfma_f32_16x16x32_f16(ah_[mi], bh_[ni], acc0[mi][ni], 0, 0, 0);
#pragma unroll
      for (int mi = 0; mi < 4; ++mi)
#pragma unroll
        for (int ni = 0; ni < 2; ++ni)
          acc1[mi][ni] = __builtin_amdgcn_mfma_f32_16x16x32_f16(ah_[mi], bl_[ni], acc1[mi][ni], 0, 0, 0);
#pragma unroll
      for (int mi = 0; mi < 4; ++mi)
#pragma unroll
        for (int ni = 0; ni < 2; ++ni)
          acc1[mi][ni] = __builtin_amdgcn_mfma_f32_16x16x32_f16(al_[mi], bh_[ni], acc1[mi][ni], 0, 0, 0);
      __syncthreads();
    }
  } else {
    // ---- 3-stage counted-vmcnt pipeline (T4, verified R15) ----
    {
      _Float16* d0 = (isA ? &tA[0][0][0] : &tB[0][0][0]) + dstoff * 512;
      for (int i = 0; i < nch; ++i)
        gload16(sbase + (long)(16 * i) * sld, d0 + i * 512);
      _Float16* d1 = (isA ? &tA[0][1][0] : &tB[0][1][0]) + dstoff * 512;
      for (int i = 0; i < nch; ++i)
        gload16(sbase + (long)(16 * i) * sld + 32, d1 + i * 512);
    }
    if (isA) asm volatile("s_waitcnt vmcnt(4)" ::: "memory");
    else     asm volatile("s_waitcnt vmcnt(2)" ::: "memory");
    __builtin_amdgcn_s_barrier();

    for (int t = 0; t < NT; ++t) {
      const int b = t % 3;
      if (t + 2 < NT) {
        const int k2 = (t + 2) * 32;
        const int b2 = (t + 2) % 3;
        _Float16* d0 = (isA ? &tA[0][b2][0] : &tB[0][b2][0]) + dstoff * 512;
        for (int i = 0; i < nch; ++i)
          gload16(sbase + (long)(16 * i) * sld + k2, d0 + i * 512);
      }

      half8 bh_[2];
#pragma unroll
      for (int ni = 0; ni < 2; ++ni)
        bh_[ni] = *(const half8*)&tB[0][b][(wc + ni * 16 + fr) * 32 + fqs];
      half8 ah_[4];
#pragma unroll
      for (int mi = 0; mi < 4; ++mi)
        ah_[mi] = *(const half8*)&tA[0][b][(wr + mi * 16 + fr) * 32 + fqs];
#pragma unroll
      for (int mi = 0; mi < 4; ++mi)
#pragma unroll
        for (int ni = 0; ni < 2; ++ni)
          acc0[mi][ni] = __builtin_amdgcn_mfma_f32_16x16x32_f16(ah_[mi], bh_[ni], acc0[mi][ni], 0, 0, 0);

      if (t + 1 < NT) {
        if (t + 2 < NT) {
          if (isA) asm volatile("s_waitcnt vmcnt(4)" ::: "memory");
          else     asm volatile("s_waitcnt vmcnt(2)" ::: "memory");
        } else {
          asm volatile("s_waitcnt vmcnt(0)" ::: "memory");
        }
        __builtin_amdgcn_s_barrier();
      }
    }
  }

#pragma unroll
  for (int mi = 0; mi < 4; ++mi) {
#pragma unroll
    for (int ni = 0; ni < 2; ++ni) {
      int gcol = bcol + wc + ni * 16 + fr;
      float bv = 0.0f;
      if constexpr (HAS_BIAS) bv = bias[(long)z1 * sBias + gcol];
#pragma unroll
      for (int v = 0; v < 4; ++v) {
        int grow = brow + wr + mi * 16 + (lane >> 4) * 4 + v;
        float val = acc0[mi][ni][v] + bv;
        if constexpr (PROD == 3) val += acc1[mi][ni][v] * 0.000244140625f;
        if constexpr (EPI == 0) {
          Cf[coff + (long)grow * ldcf + gcol] = val;
        } else if constexpr (EPI == 1) {
          _Float16 hh = (_Float16)val;
          _Float16 ll = (_Float16)((val - (float)hh) * 4096.0f);
          long ci = coff + (long)grow * ldch + gcol;
          Ch[ci] = hh; Cl[ci] = ll;
        } else if constexpr (EPI == 3) {
          Ch[coff + (long)grow * ldch + gcol] = (_Float16)val;
        } else {
          if (bcol < 2048) {       // uniform per block
            _Float16 hh = (_Float16)val;
            _Float16 ll = (_Float16)((val - (float)hh) * 4096.0f);
            long ci = (long)grow * ldch + gcol;
            Ch[ci] = hh; Cl[ci] = ll;
          } else {
            Cf[(long)grow * ldcf + (gcol - 2048)] = val;
          }
        }
      }
    }
  }
}

// ---------------------------------------------------------------------------
// bf16 MFMA GEMM (experts): 128x128 tile, K-step 32, 3-STAGE counted-vmcnt
// pipeline (T4, verified R15), bank-swizzled LDS, 48KB.  Z = expert index.
// ---------------------------------------------------------------------------
template<bool OUT_BF16, bool HAS_BIAS>
__global__ __launch_bounds__(256) void bgemm16(
    const bf16_t* __restrict__ A, const bf16_t* __restrict__ B,
    void* __restrict__ Cout, const float* __restrict__ bias,
    int K, long lda, long ldb, long ldc,
    long sA1, long sB1, long sC1, long sBias)
{
  __shared__ bf16_t tiles[2][3][128 * 32];
  const int z = blockIdx.z;
  const long coff = (long)z * sC1;
  const int brow = blockIdx.y * 128, bcol = blockIdx.x * 128;
  const int tid = threadIdx.x, lane = tid & 63, wid = tid >> 6;
  const int wr = (wid >> 1) * 64, wc = (wid & 1) * 64;
  const int fr = lane & 15;
  const int fqs = (((lane >> 4) ^ ((fr >> 1) & 3)) * 8);

  const bf16_t* src0 = (wid < 2) ? (A + (long)z * sA1) : (B + (long)z * sB1);
  const long ld = (wid < 2) ? lda : ldb;
  const int  rb = ((wid < 2) ? brow : bcol) + 64 * (wid & 1) + (lane >> 2);
  const bf16_t* srcbase = src0 + (long)rb * ld + SRC_SWZ(lane) * 8;
  const int tsel = wid >> 1, halfsel = wid & 1;

  f32x4 acc[4][4];
#pragma unroll
  for (int mi = 0; mi < 4; ++mi)
#pragma unroll
    for (int ni = 0; ni < 4; ++ni)
      acc[mi][ni] = f32x4{0.0f, 0.0f, 0.0f, 0.0f};

  const int NT = K >> 5;

  // prologue: tiles 0,1 issued; drain tile 0 (leave 4 of tile 1 in flight)
#pragma unroll
  for (int i = 0; i < 4; ++i)
    gload16(srcbase + (long)(16 * i) * ld, &tiles[tsel][0][(4 * halfsel + i) * 512]);
#pragma unroll
  for (int i = 0; i < 4; ++i)
    gload16(srcbase + (long)(16 * i) * ld + 32, &tiles[tsel][1][(4 * halfsel + i) * 512]);
  asm volatile("s_waitcnt vmcnt(4)" ::: "memory");
  __builtin_amdgcn_s_barrier();

  for (int t = 0; t < NT; ++t) {
    const int b = t % 3;
    if (t + 2 < NT) {
      const int k2 = (t + 2) * 32;
      const int b2 = (t + 2) % 3;
#pragma unroll
      for (int i = 0; i < 4; ++i)
        gload16(srcbase + (long)(16 * i) * ld + k2, &tiles[tsel][b2][(4 * halfsel + i) * 512]);
    }

    bf16x8 af[4], bfv[4];
#pragma unroll
    for (int i = 0; i < 4; ++i) {
      af[i]  = *(const bf16x8*)&tiles[0][b][(wr + i * 16 + fr) * 32 + fqs];
      bfv[i] = *(const bf16x8*)&tiles[1][b][(wc + i * 16 + fr) * 32 + fqs];
    }
#pragma unroll
    for (int mi = 0; mi < 4; ++mi)
#pragma unroll
      for (int ni = 0; ni < 4; ++ni)
        acc[mi][ni] = __builtin_amdgcn_mfma_f32_16x16x32_bf16(af[mi], bfv[ni], acc[mi][ni], 0, 0, 0);

    if (t + 1 < NT) {
      if (t + 2 < NT) asm volatile("s_waitcnt vmcnt(4)" ::: "memory");
      else            asm volatile("s_waitcnt vmcnt(0)" ::: "memory");
      __builtin_amdgcn_s_barrier();
    }
  }

#pragma unroll
  for (int mi = 0; mi < 4; ++mi) {
#pragma unroll
    for (int ni = 0; ni < 4; ++ni) {
      int gcol = bcol + wc + ni * 16 + fr;
      float bv = 0.0f;
      if constexpr (HAS_BIAS) bv = bias[(long)z * sBias + gcol];
#pragma unroll
      for (int v = 0; v < 4; ++v) {
        int grow = brow + wr + mi * 16 + (lane >> 4) * 4 + v;
        float val = acc[mi][ni][v] + bv;
        long ci = coff + (long)grow * ldc + gcol;
        if constexpr (OUT_BF16) ((bf16_t*)Cout)[ci] = (bf16_t)val;
        else                    ((float*)Cout)[ci]  = val;
      }
    }
  }
}

// ---------------------------------------------------------------------------
// 32x32 tiled transpose: dst[c][r] = (TOUT)src[r][c]; z-batched.
// ---------------------------------------------------------------------------
template<typename TOUT>
__global__ __launch_bounds__(256) void transpose_f32(
    const float* __restrict__ src, TOUT* __restrict__ dst,
    long ld_src, long ld_dst, int Z2,
    long ss1, long ss2, long sd1, long sd2)
{
  __shared__ float t[32][33];
  const int z = blockIdx.z, z1 = z / Z2, z2 = z - z1 * Z2;
  src += (long)z1 * ss1 + (long)z2 * ss2;
  dst += (long)z1 * sd1 + (long)z2 * sd2;
  const int c0 = blockIdx.x * 32, r0 = blockIdx.y * 32;
  const int tx = threadIdx.x & 31, ty = threadIdx.x >> 5;
#pragma unroll
  for (int i = 0; i < 4; ++i)
    t[ty + i * 8][tx] = src[(long)(r0 + ty + i * 8) * ld_src + c0 + tx];
  __syncthreads();
#pragma unroll
  for (int i = 0; i < 4; ++i)
    dst[(long)(c0 + ty + i * 8) * ld_dst + r0 + tx] = (TOUT)t[tx][ty + i * 8];
}

// ---------------------------------------------------------------------------
// transpose + split: dsth/dstl[c][r] = f16 limbs of src[r][c]; z-batched.
// ---------------------------------------------------------------------------
__global__ __launch_bounds__(256) void transpose_split(
    const float* __restrict__ src, _Float16* __restrict__ dh, _Float16* __restrict__ dl,
    long ld_src, long ld_dst, int Z2,
    long ss1, long ss2, long sd1, long sd2)
{
  __shared__ float t[32][33];
  const int z = blockIdx.z, z1 = z / Z2, z2 = z - z1 * Z2;
  src += (long)z1 * ss1 + (long)z2 * ss2;
  dh  += (long)z1 * sd1 + (long)z2 * sd2;
  dl  += (long)z1 * sd1 + (long)z2 * sd2;
  const int c0 = blockIdx.x * 32, r0 = blockIdx.y * 32;
  const int tx = threadIdx.x & 31, ty = threadIdx.x >> 5;
#pragma unroll
  for (int i = 0; i < 4; ++i)
    t[ty + i * 8][tx] = src[(long)(r0 + ty + i * 8) * ld_src + c0 + tx];
  __syncthreads();
#pragma unroll
  for (int i = 0; i < 4; ++i) {
    float v = t[tx][ty + i * 8];
    _Float16 h = (_Float16)v;
    _Float16 l = (_Float16)((v - (float)h) * 4096.0f);
    long idx = (long)(c0 + ty + i * 8) * ld_dst + r0 + tx;
    dh[idx] = h;
    dl[idx] = l;
  }
}

// ---------------------------------------------------------------------------
// In-place f16 row softmax (len 1024): scores row -> P row (both f16).
// ---------------------------------------------------------------------------
__global__ __launch_bounds__(256) void softmax16(
    _Float16* __restrict__ Sm, float scale)
{
  __shared__ float red[4];
  const long row = blockIdx.x;
  half4* p = (half4*)(Sm + row * 1024);
  const int tid = threadIdx.x;
  half4 hv = p[tid];
  float v0 = (float)hv.x, v1 = (float)hv.y, v2 = (float)hv.z, v3 = (float)hv.w;
  float m = fmaxf(fmaxf(v0, v1), fmaxf(v2, v3));
#pragma unroll
  for (int o = 32; o; o >>= 1) m = fmaxf(m, __shfl_xor(m, o, 64));
  if ((tid & 63) == 0) red[tid >> 6] = m;
  __syncthreads();
  m = fmaxf(fmaxf(red[0], red[1]), fmaxf(red[2], red[3]));
  __syncthreads();
  float e0 = __expf((v0 - m) * scale);
  float e1 = __expf((v1 - m) * scale);
  float e2 = __expf((v2 - m) * scale);
  float e3 = __expf((v3 - m) * scale);
  float s = e0 + e1 + e2 + e3;
#pragma unroll
  for (int o = 32; o; o >>= 1) s += __shfl_xor(s, o, 64);
  if ((tid & 63) == 0) red[tid >> 6] = s;
  __syncthreads();
  s = red[0] + red[1] + red[2] + red[3];
  float inv = 1.0f / s;
  half4 w;
  w.x = (_Float16)(e0 * inv); w.y = (_Float16)(e1 * inv);
  w.z = (_Float16)(e2 * inv); w.w = (_Float16)(e3 * inv);
  p[tid] = w;
}

// ---------------------------------------------------------------------------
// Row softmax (len 1024) fp32 IN PLACE -> packed f16 limb pair (patch path).
// ---------------------------------------------------------------------------
template<bool WRITE_LO>
__global__ __launch_bounds__(256) void softmax_pack(
    float* __restrict__ Sm, float scale)
{
  __shared__ float red[4];
  const long row = blockIdx.x;
  const float4* p = (const float4*)(Sm + row * 1024);
  const int tid = threadIdx.x;
  float4 v = p[tid];
  float m = fmaxf(fmaxf(v.x, v.y), fmaxf(v.z, v.w));
#pragma unroll
  for (int o = 32; o; o >>= 1) m = fmaxf(m, __shfl_xor(m, o, 64));
  if ((tid & 63) == 0) red[tid >> 6] = m;
  __syncthreads();
  m = fmaxf(fmaxf(red[0], red[1]), fmaxf(red[2], red[3]));
  __syncthreads();
  float e0 = __expf((v.x - m) * scale);
  float e1 = __expf((v.y - m) * scale);
  float e2 = __expf((v.z - m) * scale);
  float e3 = __expf((v.w - m) * scale);
  float s = e0 + e1 + e2 + e3;
#pragma unroll
  for (int o = 32; o; o >>= 1) s += __shfl_xor(s, o, 64);
  if ((tid & 63) == 0) red[tid >> 6] = s;
  __syncthreads();
  s = red[0] + red[1] + red[2] + red[3];
  float inv = 1.0f / s;
  float p0 = e0 * inv, p1 = e1 * inv, p2 = e2 * inv, p3 = e3 * inv;
  half4 h;
  h.x = (_Float16)p0; h.y = (_Float16)p1; h.z = (_Float16)p2; h.w = (_Float16)p3;
  _Float16* base = (_Float16*)Sm + row * 2048;
  ((half4*)base)[tid] = h;
  if constexpr (WRITE_LO) {
    half4 l;
    l.x = (_Float16)((p0 - (float)h.x) * 4096.0f);
    l.y = (_Float16)((p1 - (float)h.y) * 4096.0f);
    l.z = (_Float16)((p2 - (float)h.z) * 4096.0f);
    l.w = (_Float16)((p3 - (float)h.w) * 4096.0f);
    ((half4*)(base + 1024))[tid] = l;
  }
}

// ---------------------------------------------------------------------------
// Fused: y1 = LN(x + attn) -> bf16 y1b; gate logits, argmax idx, gval;
// borderline tokens (gap < TAU) appended to per-sequence lists (cap 128).
// ---------------------------------------------------------------------------
__global__ __launch_bounds__(256) void add_ln_gate(
    const float* __restrict__ x, const float* __restrict__ attn,
    const float* __restrict__ g, const float* __restrict__ be,
    const float* __restrict__ wg, bf16_t* __restrict__ yb,
    int* __restrict__ idx, float* __restrict__ gval,
    int* __restrict__ bcnt16, int* __restrict__ blist16)
{
  __shared__ float red[4];
  __shared__ float lred[4][8];
  const long s = blockIdx.x;
  const int tid = threadIdx.x;
  const int lane = tid & 63, w = tid >> 6;
  float4 va = ((const float4*)(x + s * 1024))[tid];
  float4 vb = ((const float4*)(attn + s * 1024))[tid];
  float v0 = va.x + vb.x, v1 = va.y + vb.y, v2 = va.z + vb.z, v3 = va.w + vb.w;
  float sum = v0 + v1 + v2 + v3;
#pragma unroll
  for (int o = 32; o; o >>= 1) sum += __shfl_xor(sum, o, 64);
  if (lane == 0) red[w] = sum;
  __syncthreads();
  float mu = (red[0] + red[1] + red[2] + red[3]) * (1.0f / 1024.0f);
  __syncthreads();
  float d0 = v0 - mu, d1 = v1 - mu, d2 = v2 - mu, d3 = v3 - mu;
  float ss = d0 * d0 + d1 * d1 + d2 * d2 + d3 * d3;
#pragma unroll
  for (int o = 32; o; o >>= 1) ss += __shfl_xor(ss, o, 64);
  if (lane == 0) red[w] = ss;
  __syncthreads();
  float var = (red[0] + red[1] + red[2] + red[3]) * (1.0f / 1024.0f);
  float rstd = rsqrtf(var + 1e-5f);
  float4 vg  = ((const float4*)g)[tid];
  float4 vbe = ((const float4*)be)[tid];
  float y0 = d0 * rstd * vg.x + vbe.x;
  float y1v = d1 * rstd * vg.y + vbe.y;
  float y2v = d2 * rstd * vg.z + vbe.z;
  float y3 = d3 * rstd * vg.w + vbe.w;
  bf16x4 ov = { (bf16_t)y0, (bf16_t)y1v, (bf16_t)y2v, (bf16_t)y3 };
  *(bf16x4*)(yb + s * 1024 + tid * 4) = ov;
  float lg[8];
  const float* w0 = wg + (long)(tid * 4) * 8;
#pragma unroll
  for (int e = 0; e < 8; ++e)
    lg[e] = y0 * w0[e] + y1v * w0[8 + e] + y2v * w0[16 + e] + y3 * w0[24 + e];
#pragma unroll
  for (int e = 0; e < 8; ++e) {
#pragma unroll
    for (int o = 32; o; o >>= 1) lg[e] += __shfl_xor(lg[e], o, 64);
  }
  if (lane == 0) {
#pragma unroll
    for (int e = 0; e < 8; ++e) lred[w][e] = lg[e];
  }
  __syncthreads();
  if (tid == 0) {
    float Lg[8];
#pragma unroll
    for (int e = 0; e < 8; ++e)
      Lg[e] = lred[0][e] + lred[1][e] + lred[2][e] + lred[3][e];
    float best = Lg[0], second = -1e30f; int bi = 0;
#pragma unroll
    for (int e = 1; e < 8; ++e) {
      if (Lg[e] > best) { second = best; best = Lg[e]; bi = e; }
      else if (Lg[e] > second) second = Lg[e];
    }
    float sm = 0.0f;
#pragma unroll
    for (int e = 0; e < 8; ++e) sm += __expf(Lg[e] - best);
    idx[s] = bi;
    gval[s] = 1.0f / sm;
    if (best - second < TAU_) {
      int n = (int)(s & 15);
      int p = atomicAdd(&bcnt16[n], 1);
      if (p < 128) blist16[n * 128 + p] = (int)s;
    }
  }
}

// ---------------------------------------------------------------------------
__global__ void zero16(int* __restrict__ p)
{
  if (threadIdx.x < 16) p[threadIdx.x] = 0;
}

// ---------------------------------------------------------------------------
// Gather borderline Q rows (limbs) into padded [16*128][1024]; pad rows zero.
// ---------------------------------------------------------------------------
__global__ __launch_bounds__(64) void qp_gather(
    const int* __restrict__ bcnt16, const int* __restrict__ blist16,
    const _Float16* __restrict__ QKh, const _Float16* __restrict__ QKl,
    _Float16* __restrict__ Qph, _Float16* __restrict__ Qpl)
{
  const int b = blockIdx.x;
  const int n = b >> 7, p = b & 127;
  const int t = threadIdx.x;
  half8* dh = (half8*)(Qph + (long)b * 1024);
  half8* dl = (half8*)(Qpl + (long)b * 1024);
  int cnt = bcnt16[n]; if (cnt > 128) cnt = 128;
  if (p < cnt) {
    long srow = (long)blist16[b] * 2048;
    const half8* sh = (const half8*)(QKh + srow);
    const half8* sl = (const half8*)(QKl + srow);
    dh[t * 2]     = sh[t * 2];
    dh[t * 2 + 1] = sh[t * 2 + 1];
    dl[t * 2]     = sl[t * 2];
    dl[t * 2 + 1] = sl[t * 2 + 1];
  } else {
    half8 z;
#pragma unroll
    for (int i = 0; i < 8; ++i) z[i] = (_Float16)0.0f;
    dh[t * 2] = z; dh[t * 2 + 1] = z;
    dl[t * 2] = z; dl[t * 2 + 1] = z;
  }
}

// ---------------------------------------------------------------------------
// Final fix: exact y1 row + logits from exact attn_p; overwrite idx/gval.
// ---------------------------------------------------------------------------
__global__ __launch_bounds__(256) void gate_fix(
    const int* __restrict__ bcnt16, const int* __restrict__ blist16,
    const float* __restrict__ attn_p, const float* __restrict__ x,
    const float* __restrict__ g, const float* __restrict__ be,
    const float* __restrict__ wg,
    int* __restrict__ idx, float* __restrict__ gval)
{
  const int b = blockIdx.x;
  const int n = b >> 7, p = b & 127;
  int cnt = bcnt16[n]; if (cnt > 128) cnt = 128;
  if (p >= cnt) return;
  const long s = blist16[b];
  __shared__ float red[4];
  __shared__ float lred[4][8];
  const int tid = threadIdx.x;
  const int lane = tid & 63, w = tid >> 6;
  float4 va = ((const float4*)(x + s * 1024))[tid];
  float4 vb = ((const float4*)(attn_p + (long)b * 1024))[tid];
  float v0 = va.x + vb.x, v1 = va.y + vb.y, v2 = va.z + vb.z, v3 = va.w + vb.w;
  float sum = v0 + v1 + v2 + v3;
#pragma unroll
  for (int o = 32; o; o >>= 1) sum += __shfl_xor(sum, o, 64);
  if (lane == 0) red[w] = sum;
  __syncthreads();
  float mu = (red[0] + red[1] + red[2] + red[3]) * (1.0f / 1024.0f);
  __syncthreads();
  float d0 = v0 - mu, d1 = v1 - mu, d2 = v2 - mu, d3 = v3 - mu;
  float ss = d0 * d0 + d1 * d1 + d2 * d2 + d3 * d3;
#pragma unroll
  for (int o = 32; o; o >>= 1) ss += __shfl_xor(ss, o, 64);
  if (lane == 0) red[w] = ss;
  __syncthreads();
  float var = (red[0] + red[1] + red[2] + red[3]) * (1.0f / 1024.0f);
  float rstd = rsqrtf(var + 1e-5f);
  float4 vg  = ((const float4*)g)[tid];
  float4 vbe = ((const float4*)be)[tid];
  float y0 = d0 * rstd * vg.x + vbe.x;
  float y1v = d1 * rstd * vg.y + vbe.y;
  float y2v = d2 * rstd * vg.z + vbe.z;
  float y3 = d3 * rstd * vg.w + vbe.w;
  float lg[8];
  const float* w0 = wg + (long)(tid * 4) * 8;
#pragma unroll
  for (int e = 0; e < 8; ++e)
    lg[e] = y0 * w0[e] + y1v * w0[8 + e] + y2v * w0[16 + e] + y3 * w0[24 + e];
#pragma unroll
  for (int e = 0; e < 8; ++e) {
#pragma unroll
    for (int o = 32; o; o >>= 1) lg[e] += __shfl_xor(lg[e], o, 64);
  }
  if (lane == 0) {
#pragma unroll
    for (int e = 0; e < 8; ++e) lred[w][e] = lg[e];
  }
  __syncthreads();
  if (tid == 0) {
    float Lg[8];
#pragma unroll
    for (int e = 0; e < 8; ++e)
      Lg[e] = lred[0][e] + lred[1][e] + lred[2][e] + lred[3][e];
    float best = Lg[0]; int bi = 0;
#pragma unroll
    for (int e = 1; e < 8; ++e) { if (Lg[e] > best) { best = Lg[e]; bi = e; } }
    float sm = 0.0f;
#pragma unroll
    for (int e = 0; e < 8; ++e) sm += __expf(Lg[e] - best);
    idx[s] = bi;
    gval[s] = 1.0f / sm;
  }
}

// ---------------------------------------------------------------------------
// out = LN(y1b + (keep ? gval * ymoe[slot] : 0); g, be)   [bf16 inputs]
// ---------------------------------------------------------------------------
__global__ __launch_bounds__(256) void combine_ln(
    const bf16_t* __restrict__ y1b, const bf16_t* __restrict__ ymoe,
    const int* __restrict__ slot, const float* __restrict__ gval,
    const float* __restrict__ g, const float* __restrict__ be,
    float* __restrict__ out)
{
  __shared__ float red[4];
  const long s = blockIdx.x;
  const int tid = threadIdx.x;
  const int lane = tid & 63, w = tid >> 6;
  int sl = slot[s];
  bool keep = sl < ESLOTS_;
  float gv = keep ? gval[s] : 0.0f;
  long mrow = keep ? (long)sl * 1024 : 0;
  bf16x4 ya = *(const bf16x4*)(y1b + s * 1024 + tid * 4);
  bf16x4 ym = *(const bf16x4*)(ymoe + mrow + tid * 4);
  float v0 = (float)ya[0] + gv * (float)ym[0];
  float v1 = (float)ya[1] + gv * (float)ym[1];
  float v2 = (float)ya[2] + gv * (float)ym[2];
  float v3 = (float)ya[3] + gv * (float)ym[3];
  float sum = v0 + v1 + v2 + v3;
#pragma unroll
  for (int o = 32; o; o >>= 1) sum += __shfl_xor(sum, o, 64);
  if (lane == 0) red[w] = sum;
  __syncthreads();
  float mu = (red[0] + red[1] + red[2] + red[3]) * (1.0f / 1024.0f);
  __syncthreads();
  float d0 = v0 - mu, d1 = v1 - mu, d2 = v2 - mu, d3 = v3 - mu;
  float ss = d0 * d0 + d1 * d1 + d2 * d2 + d3 * d3;
#pragma unroll
  for (int o = 32; o; o >>= 1) ss += __shfl_xor(ss, o, 64);
  if (lane == 0) red[w] = ss;
  __syncthreads();
  float var = (red[0] + red[1] + red[2] + red[3]) * (1.0f / 1024.0f);
  float rstd = rsqrtf(var + 1e-5f);
  float4 vg  = ((const float4*)g)[tid];
  float4 vbe = ((const float4*)be)[tid];
  float4 ov = {d0 * rstd * vg.x + vbe.x, d1 * rstd * vg.y + vbe.y,
               d2 * rstd * vg.z + vbe.z, d3 * rstd * vg.w + vbe.w};
  ((float4*)(out + s * 1024))[tid] = ov;
}

// ---------------------------------------------------------------------------
// Parallel routing scan (R17), token-order-exact, 3 kernels:
// rs_count: per-block (128 tokens) per-expert histogram + tfs init.
// rs_scan:  exclusive prefix over blocks per expert (1 small block).
// rs_emit:  in-block order-preserving rank + global offset -> slot/tfs.
// ---------------------------------------------------------------------------
__global__ __launch_bounds__(128) void rs_count(
    const int* __restrict__ idx, int* __restrict__ bcounts, int* __restrict__ tfs)
{
  __shared__ int cnt[8];
  const int b = blockIdx.x, t = threadIdx.x;
  if (t < 8) cnt[t] = 0;
  __syncthreads();
  int e = idx[b * 128 + t];
  atomicAdd(&cnt[e], 1);
  tfs[b * 128 + t] = -1;
  __syncthreads();
  if (t < 8) bcounts[b * 8 + t] = cnt[t];
}

__global__ __launch_bounds__(64) void rs_scan(
    const int* __restrict__ bcounts, int* __restrict__ boffs)
{
  const int e = threadIdx.x;
  if (e < 8) {
    int acc = 0;
    for (int b = 0; b < 128; ++b) {
      boffs[b * 8 + e] = acc;
      acc += bcounts[b * 8 + e];
    }
  }
}

__global__ __launch_bounds__(128) void rs_emit(
    const int* __restrict__ idx, const int* __restrict__ boffs,
    int* __restrict__ slot, int* __restrict__ tfs)
{
  __shared__ int le[128];
  const int b = blockIdx.x, t = threadIdx.x;
  const int s = b * 128 + t;
  int e = idx[s];
  le[t] = e;
  __syncthreads();
  int loc = boffs[b * 8 + e];
  for (int u = 0; u < t; ++u) loc += (le[u] == e) ? 1 : 0;
  int sl = (loc < CAP_) ? e * CAP_ + loc : ESLOTS_;
  slot[s] = sl;
  if (sl < ESLOTS_) tfs[sl] = s;
}

// ---------------------------------------------------------------------------
// Gather dispatch rows (bf16): disp[slot] = y1b[token] or zeros.
// ---------------------------------------------------------------------------
__global__ void dispatch_rows(
    const int* __restrict__ tfs, const bf16_t* __restrict__ y1b,
    bf16_t* __restrict__ disp)
{
  const int row = blockIdx.x;
  const int t = tfs[row];
  bf16x8* d = (bf16x8*)(disp + (long)row * 1024);
  if (t >= 0) {
    const bf16x8* sp = (const bf16x8*)(y1b + (long)t * 1024);
    d[threadIdx.x] = sp[threadIdx.x];
  } else {
    bf16x8 zv;
#pragma unroll
    for (int i = 0; i < 8; ++i) zv[i] = (bf16_t)0.0f;
    d[threadIdx.x] = zv;
  }
}

// ---------------------------------------------------------------------------
__global__ void fill_val(float* __restrict__ p, float v, long n)
{
  long i = (long)blockIdx.x * blockDim.x + threadIdx.x;
  long stride = (long)gridDim.x * blockDim.x;
  for (; i < n; i += stride) p[i] = v;
}

// ---------------------------------------------------------------------------
extern "C" void kernel_launch(void* const* d_in, const int* in_sizes, int n_in,
                              void* d_out, int out_size, void* d_ws, size_t ws_size,
                              hipStream_t stream)
{
  const float* x    = (const float*)d_in[0];
  const float* Wqkv = (const float*)d_in[1];
  const float* bqkv = (const float*)d_in[2];
  const float* Wo   = (const float*)d_in[3];
  const float* bo   = (const float*)d_in[4];
  const float* g1   = (const float*)d_in[5];
  const float* b1n  = (const float*)d_in[6];
  const float* g2   = (const float*)d_in[7];
  const float* b2n  = (const float*)d_in[8];
  const float* wg   = (const float*)d_in[9];
  const float* w1   = (const float*)d_in[10];
  const float* b1e  = (const float*)d_in[11];
  const float* w2   = (const float*)d_in[12];
  const float* b2e  = (const float*)d_in[13];
  float* out = (float*)d_out;

  const size_t MB = 1ull << 20;
  const size_t REQUIRED = 384 * MB;
  if (ws_size < REQUIRED) {
    fill_val<<<2048, 256, 0, stream>>>(out, (float)(ws_size >> 20), (long)out_size);
    return;
  }

  char* ws = (char*)d_ws;
  // Region map v4 (audited) — same as R14/R15:
  _Float16* Xh   = (_Float16*)(ws + 0);
  _Float16* Xl   = (_Float16*)(ws + 32 * MB);
  _Float16* Wqh  = (_Float16*)(ws + 64 * MB);
  _Float16* Wql  = (_Float16*)(ws + 70 * MB);
  _Float16* scores16 = (_Float16*)(ws + 0);
  _Float16* Woh  = (_Float16*)(ws + 64 * MB);
  _Float16* Wol  = (_Float16*)(ws + 66 * MB);
  _Float16* QKh  = (_Float16*)(ws + 80 * MB);
  _Float16* QKl  = (_Float16*)(ws + 144 * MB);
  float*    Vf32 = (float*)(ws + 208 * MB);
  _Float16* oh   = (_Float16*)(ws + 208 * MB);
  _Float16* vTh  = (_Float16*)(ws + 272 * MB);
  _Float16* vTl  = (_Float16*)(ws + 304 * MB);
  float*    attn = (float*)(ws + 0);
  bf16_t*   y1b  = (bf16_t*)(ws + 208 * MB);
  float*    scp   = (float*)(ws + 0);             // 32MB patch scores
  _Float16* Qph   = (_Float16*)(ws + 32 * MB);
  _Float16* Qpl   = (_Float16*)(ws + 36 * MB);
  _Float16* o_ph  = (_Float16*)(ws + 40 * MB);
  _Float16* o_pl  = (_Float16*)(ws + 44 * MB);
  float*    attnp = (float*)(ws + 48 * MB);
  int*      idx  = (int*)(ws + 336 * MB);
  int*      slot = idx + S_;
  float*    gval = (float*)(slot + S_);
  int*      tfs  = (int*)(gval + S_);
  int*      bcnt16  = tfs + S_;
  int*      blist16 = bcnt16 + 16;
  int*      bcounts = blist16 + 2048;   // 128*8 ints
  int*      boffs   = bcounts + 1024;   // 128*8 ints
  bf16_t*   disp = (bf16_t*)(ws + 272 * MB);
  bf16_t*   W1t  = (bf16_t*)(ws + 0);
  bf16_t*   W2t  = (bf16_t*)(ws + 0);
  bf16_t*   h    = (bf16_t*)(ws + 80 * MB);
  bf16_t*   ymoe = (bf16_t*)(ws + 304 * MB);

  // 0. zero borderline counters early
  zero16<<<1, 64, 0, stream>>>(bcnt16);

  // 1. pre-split x and Wqkv to f16 limbs
  split2<<<4096, 256, 0, stream>>>(x, Xh, Xl, (long)S_ * D_ / 4);
  split2<<<2048, 256, 0, stream>>>(Wqkv, Wqh, Wql, (long)3 * D_ * D_ / 4);

  // 2. qkv GEMM (3-product, 2-phase as verified R15): Q,K -> limbs; V -> fp32
  hgemm3s<2, true, 3><<<dim3(48, 128, 1), 256, 0, stream>>>(
      Xh, Xl, Wqh, Wql, Vf32, QKh, QKl, bqkv,
      D_, D_, D_, D_, 2 * D_,
      1, 0, 0, 0, 0, 0, 0, 0);

  // 3. split Wo
  split2<<<1024, 256, 0, stream>>>(Wo, Woh, Wol, (long)D_ * D_ / 4);

  // 4. vT limbs [n,h][HD][L] from Vf32 [S][D]
  transpose_split<<<dim3(HD_ / 32, L_ / 32, 64), 256, 0, stream>>>(
      Vf32, vTh, vTl, (long)N_ * D_, L_,
      H_, D_, HD_, (long)H_ * HD_ * L_, (long)HD_ * L_);

  // 5. attention main path (1-product f16, 3-stage pipeline), 2 groups of 8
  for (int g = 0; g < 2; ++g) {
    const long qko = (long)g * 8 * 2048;
    hgemm3s<3, false, 1><<<dim3(16, 8, 32), 256, 0, stream>>>(
        QKh + qko, QKl + qko, QKh + qko + 1024, QKl + qko + 1024,
        nullptr, scores16, nullptr, nullptr,
        HD_, (long)N_ * 2048, (long)N_ * 2048, 0, L_,
        H_, 2048, 256, 2048, 256, (long)H_ * L_ * L_, (long)L_ * L_, 0);
    softmax16<<<8 * H_ * L_, 256, 0, stream>>>(scores16, 0.0625f);
    hgemm3s<3, false, 1><<<dim3(4, 8, 32), 256, 0, stream>>>(
        scores16, nullptr,
        vTh + (long)g * 8 * H_ * HD_ * L_, vTl + (long)g * 8 * H_ * HD_ * L_,
        nullptr, oh + (long)g * 8 * D_, nullptr, nullptr,
        L_, L_, L_, 0, (long)N_ * D_,
        H_, (long)H_ * L_ * L_, (long)L_ * L_,
        (long)H_ * HD_ * L_, (long)HD_ * L_, D_, HD_, 0);
  }

  // 6. attn = o @ Wo^T + bo   (1-product, 3-stage)
  hgemm3s<0, true, 1><<<dim3(16, 128, 1), 256, 0, stream>>>(
      oh, nullptr, Woh, Wol, attn, nullptr, nullptr, bo,
      D_, D_, D_, D_, 0,
      1, 0, 0, 0, 0, 0, 0, 0);

  // 7. fused LN + gate + borderline detection (writes y1b bf16)
  add_ln_gate<<<S_, 256, 0, stream>>>(x, attn, g1, b1n, wg, y1b,
                                      idx, gval, bcnt16, blist16);

  // 8. exact-gate patch for borderline tokens (3-product grade, 2-phase)
  qp_gather<<<2048, 64, 0, stream>>>(bcnt16, blist16, QKh, QKl, Qph, Qpl);
  hgemm3s<0, false, 3><<<dim3(16, 1, 64), 256, 0, stream>>>(
      Qph, Qpl, QKh + 1024, QKl + 1024, scp, nullptr, nullptr, nullptr,
      HD_, 1024, (long)N_ * 2048, 1024, 0,
      4, (long)128 * 1024, 256, 2048, 256,
      (long)4 * 128 * 1024, (long)128 * 1024, 0);
  softmax_pack<true><<<64 * 128, 256, 0, stream>>>(scp, 0.0625f);
  hgemm3s<1, false, 3><<<dim3(4, 1, 64), 256, 0, stream>>>(
      (_Float16*)scp, (_Float16*)scp + 1024, vTh, vTl,
      nullptr, o_ph, o_pl, nullptr,
      L_, 2048, L_, 0, 1024,
      4, (long)4 * 128 * 2048, (long)128 * 2048,
      (long)H_ * HD_ * L_, (long)HD_ * L_,
      (long)128 * 1024, 256, 0);
  hgemm3s<0, true, 3><<<dim3(16, 16, 1), 256, 0, stream>>>(
      o_ph, o_pl, Woh, Wol, attnp, nullptr, nullptr, bo,
      D_, D_, D_, D_, 0,
      1, 0, 0, 0, 0, 0, 0, 0);
  gate_fix<<<2048, 256, 0, stream>>>(bcnt16, blist16, attnp, x,
                                     g1, b1n, wg, idx, gval);

  // 9. token-order routing scan + capacity drop (parallel, 3 kernels)
  rs_count<<<128, 128, 0, stream>>>(idx, bcounts, tfs);
  rs_scan<<<1, 64, 0, stream>>>(bcounts, boffs);
  rs_emit<<<128, 128, 0, stream>>>(idx, boffs, slot, tfs);

  // 10. gather dispatch rows (bf16)
  dispatch_rows<<<ESLOTS_, 128, 0, stream>>>(tfs, y1b, disp);

  // 11. W1t[e][FF][D] bf16 from w1 fp32 (patch scratch dead)
  transpose_f32<bf16_t><<<dim3(FF_ / 32, D_ / 32, E_), 256, 0, stream>>>(
      w1, W1t, FF_, D_, 1, (long)D_ * FF_, 0, (long)FF_ * D_, 0);

  // 12. h[e] = disp[e] @ w1[e] + b1[e]; 3-stage bgemm, grid (32,16,8)
  bgemm16<true, true><<<dim3(32, 16, 8), 256, 0, stream>>>(
      disp, W1t, h, b1e, D_, D_, D_, FF_,
      (long)CAP_ * D_, (long)FF_ * D_, (long)CAP_ * FF_, FF_);

  // 13. W2t[e][D][FF] bf16 from w2 fp32
  transpose_f32<bf16_t><<<dim3(D_ / 32, FF_ / 32, E_), 256, 0, stream>>>(
      w2, W2t, D_, FF_, 1, (long)FF_ * D_, 0, (long)D_ * FF_, 0);

  // 14. ymoe[e] (bf16) = h[e] @ w2[e] + b2[e]; grid (8,16,8)
  bgemm16<true, true><<<dim3(8, 16, 8), 256, 0, stream>>>(
      h, W2t, ymoe, b2e, FF_, FF_, FF_, D_,
      (long)CAP_ * FF_, (long)D_ * FF_, (long)CAP_ * D_, D_);

  // 15. out = LN(y1b + combine)
  combine_ln<<<S_, 256, 0, stream>>>(y1b, ymoe, slot, gval, g2, b2n, out);
}

// Round 18
// 1476.501 us; speedup vs baseline: 1.0186x; 1.0002x over previous
//
#include <hip/hip_runtime.h>
#include <hip/hip_bf16.h>

typedef __bf16 bf16_t;
typedef bf16_t bf16x4 __attribute__((ext_vector_type(4)));
typedef bf16_t bf16x8 __attribute__((ext_vector_type(8)));
typedef float  f32x4  __attribute__((ext_vector_type(4)));
typedef _Float16 half4 __attribute__((ext_vector_type(4)));
typedef _Float16 half8 __attribute__((ext_vector_type(8)));

// Problem constants
#define L_  1024
#define N_  16
#define S_  16384          // L*N tokens
#define D_  1024
#define H_  4
#define HD_ 256
#define E_  8
#define FF_ 4096
#define CAP_ 2048
#define ESLOTS_ (E_*CAP_)  // 16384
#define TAU_ 0.03f         // borderline gate-gap threshold

// ---------------------------------------------------------------------------
// async global->LDS, 16B per lane: dest = ldsbase + lane*16 (wave-uniform base)
// ---------------------------------------------------------------------------
__device__ __forceinline__ void gload16(const void* g, void* l) {
  __builtin_amdgcn_global_load_lds(
      (const __attribute__((address_space(1))) void*)g,
      (__attribute__((address_space(3))) void*)l,
      16, 0, 0);
}

// LDS bank swizzle (verified R10: conflicts -> 0). inverse-swizzled SOURCE +
// swizzled READ, LDS stays linear for global_load_lds.
#define SRC_SWZ(lane) (((lane) & 3) ^ (((lane) >> 3) & 3))

// ---------------------------------------------------------------------------
// split2: fp32 -> f16 two-limb (hi, lo*4096)
// ---------------------------------------------------------------------------
__global__ __launch_bounds__(256) void split2(
    const float* __restrict__ in, _Float16* __restrict__ oh,
    _Float16* __restrict__ ol, long n4)
{
  long i = (long)blockIdx.x * blockDim.x + threadIdx.x;
  long stride = (long)gridDim.x * blockDim.x;
  for (; i < n4; i += stride) {
    float4 v = ((const float4*)in)[i];
    half4 h, l;
    h.x = (_Float16)v.x; l.x = (_Float16)((v.x - (float)h.x) * 4096.0f);
    h.y = (_Float16)v.y; l.y = (_Float16)((v.y - (float)h.y) * 4096.0f);
    h.z = (_Float16)v.z; l.z = (_Float16)((v.z - (float)h.z) * 4096.0f);
    h.w = (_Float16)v.w; l.w = (_Float16)((v.w - (float)h.w) * 4096.0f);
    ((half4*)oh)[i] = h;
    ((half4*)ol)[i] = l;
  }
}

// ---------------------------------------------------------------------------
// MFMA GEMM on pre-split f16 limbs.
// PROD==3: C = Ah*Bh + (Ah*Bl + Al*Bh)/4096  (fp32-class; 2-phase dbuf loop,
//          byte-identical schedule to the R12/R15-passing kernel, 48KB LDS)
// PROD==1: C = Ah*Bh  (f16-class) with 3-STAGE COUNTED-VMCNT PIPELINE (T4,
//          R15-verified): triple-buffer LDS; iter t issues tile t+2, computes
//          tile t, drains only tile t+1 (vmcnt=nch), raw s_barrier.
// Block 128x64, K-step 32, 4 waves (2x2), per-wave 64x32, bank-swizzled LDS.
// EPI: 0 fp32 C; 1 limb-pair C; 2 qkv special; 3 f16-only.
// Row-block = blockIdx.Y, col-block = blockIdx.X (L2 locality, R13).
// ---------------------------------------------------------------------------
template<int EPI, bool HAS_BIAS, int PROD>
__global__ __launch_bounds__(256) void hgemm3s(
    const _Float16* __restrict__ Ah, const _Float16* __restrict__ Al,
    const _Float16* __restrict__ Bh, const _Float16* __restrict__ Bl,
    float* __restrict__ Cf, _Float16* __restrict__ Ch, _Float16* __restrict__ Cl,
    const float* __restrict__ bias,
    int K, long lda, long ldb, long ldcf, long ldch,
    int Z2, long sA1, long sA2, long sB1, long sB2, long sC1, long sC2, long sBias)
{
  constexpr int NL   = (PROD == 3) ? 2 : 1;
  constexpr int NBUF = (PROD == 3) ? 2 : 3;
  __shared__ _Float16 tA[NL][NBUF][128 * 32];
  __shared__ _Float16 tB[NL][NBUF][64 * 32];
  const int z  = blockIdx.z;
  const int z1 = z / Z2, z2 = z - z1 * Z2;
  const long aoff = (long)z1 * sA1 + (long)z2 * sA2;
  const long boff = (long)z1 * sB1 + (long)z2 * sB2;
  const long coff = (long)z1 * sC1 + (long)z2 * sC2;
  const int brow = blockIdx.y * 128, bcol = blockIdx.x * 64;
  const int tid = threadIdx.x, lane = tid & 63, wid = tid >> 6;
  const int wr = (wid >> 1) * 64, wc = (wid & 1) * 32;
  const int fr = lane & 15;
  const int fqs = (((lane >> 4) ^ ((fr >> 1) & 3)) * 8);

  // staging roles
  const bool isA = (wid < 2);
  int limb, dstoff, nch;
  const _Float16* ssrc;
  if constexpr (PROD == 3) {
    limb = wid & 1; nch = isA ? 8 : 4; dstoff = 0;
    ssrc = (wid == 0) ? Ah : (wid == 1) ? Al : (wid == 2) ? Bh : Bl;
  } else {
    limb = 0; nch = isA ? 4 : 2; dstoff = (wid & 1) * nch;
    ssrc = isA ? Ah : Bh;
  }
  const long sld = isA ? lda : ldb;
  const long soff = isA ? aoff : boff;
  int srow = (isA ? brow : bcol) + (lane >> 2);
  if constexpr (PROD == 1) srow += (wid & 1) * (isA ? 64 : 32);
  const _Float16* sbase = ssrc + soff + (long)srow * sld + SRC_SWZ(lane) * 8;

  f32x4 acc0[4][2], acc1[4][2];
#pragma unroll
  for (int mi = 0; mi < 4; ++mi)
#pragma unroll
    for (int ni = 0; ni < 2; ++ni) {
      acc0[mi][ni] = f32x4{0.f, 0.f, 0.f, 0.f};
      acc1[mi][ni] = f32x4{0.f, 0.f, 0.f, 0.f};
    }

  const int NT = K >> 5;

  if constexpr (PROD == 3) {
    // ---- 2-phase dbuf loop (verified R12/R15) ----
    {
      _Float16* d0 = (isA ? &tA[limb][0][0] : &tB[limb][0][0]) + dstoff * 512;
      for (int i = 0; i < nch; ++i)
        gload16(sbase + (long)(16 * i) * sld, d0 + i * 512);
    }
    __syncthreads();

    for (int t = 0; t < NT; ++t) {
      const int cur = t & 1;
      if (t + 1 < NT) {
        const int k1 = (t + 1) * 32;
        _Float16* d0 = (isA ? &tA[limb][cur ^ 1][0] : &tB[limb][cur ^ 1][0]) + dstoff * 512;
        for (int i = 0; i < nch; ++i)
          gload16(sbase + (long)(16 * i) * sld + k1, d0 + i * 512);
      }

      half8 bh_[2], bl_[2];
#pragma unroll
      for (int ni = 0; ni < 2; ++ni) {
        bh_[ni] = *(const half8*)&tB[0][cur][(wc + ni * 16 + fr) * 32 + fqs];
        bl_[ni] = *(const half8*)&tB[1][cur][(wc + ni * 16 + fr) * 32 + fqs];
      }
      half8 ah_[4], al_[4];
#pragma unroll
      for (int mi = 0; mi < 4; ++mi) {
        ah_[mi] = *(const half8*)&tA[0][cur][(wr + mi * 16 + fr) * 32 + fqs];
        al_[mi] = *(const half8*)&tA[1][cur][(wr + mi * 16 + fr) * 32 + fqs];
      }
#pragma unroll
      for (int mi = 0; mi < 4; ++mi)
#pragma unroll
        for (int ni = 0; ni < 2; ++ni)
          acc0[mi][ni] = __builtin_amdgcn_mfma_f32_16x16x32_f16(ah_[mi], bh_[ni], acc0[mi][ni], 0, 0, 0);
#pragma unroll
      for (int mi = 0; mi < 4; ++mi)
#pragma unroll
        for (int ni = 0; ni < 2; ++ni)
          acc1[mi][ni] = __builtin_amdgcn_mfma_f32_16x16x32_f16(ah_[mi], bl_[ni], acc1[mi][ni], 0, 0, 0);
#pragma unroll
      for (int mi = 0; mi < 4; ++mi)
#pragma unroll
        for (int ni = 0; ni < 2; ++ni)
          acc1[mi][ni] = __builtin_amdgcn_mfma_f32_16x16x32_f16(al_[mi], bh_[ni], acc1[mi][ni], 0, 0, 0);
      __syncthreads();
    }
  } else {
    // ---- 3-stage counted-vmcnt pipeline (T4, verified R15) ----
    {
      _Float16* d0 = (isA ? &tA[0][0][0] : &tB[0][0][0]) + dstoff * 512;
      for (int i = 0; i < nch; ++i)
        gload16(sbase + (long)(16 * i) * sld, d0 + i * 512);
      _Float16* d1 = (isA ? &tA[0][1][0] : &tB[0][1][0]) + dstoff * 512;
      for (int i = 0; i < nch; ++i)
        gload16(sbase + (long)(16 * i) * sld + 32, d1 + i * 512);
    }
    if (isA) asm volatile("s_waitcnt vmcnt(4)" ::: "memory");
    else     asm volatile("s_waitcnt vmcnt(2)" ::: "memory");
    __builtin_amdgcn_s_barrier();

    for (int t = 0; t < NT; ++t) {
      const int b = t % 3;
      if (t + 2 < NT) {
        const int k2 = (t + 2) * 32;
        const int b2 = (t + 2) % 3;
        _Float16* d0 = (isA ? &tA[0][b2][0] : &tB[0][b2][0]) + dstoff * 512;
        for (int i = 0; i < nch; ++i)
          gload16(sbase + (long)(16 * i) * sld + k2, d0 + i * 512);
      }

      half8 bh_[2];
#pragma unroll
      for (int ni = 0; ni < 2; ++ni)
        bh_[ni] = *(const half8*)&tB[0][b][(wc + ni * 16 + fr) * 32 + fqs];
      half8 ah_[4];
#pragma unroll
      for (int mi = 0; mi < 4; ++mi)
        ah_[mi] = *(const half8*)&tA[0][b][(wr + mi * 16 + fr) * 32 + fqs];
#pragma unroll
      for (int mi = 0; mi < 4; ++mi)
#pragma unroll
        for (int ni = 0; ni < 2; ++ni)
          acc0[mi][ni] = __builtin_amdgcn_mfma_f32_16x16x32_f16(ah_[mi], bh_[ni], acc0[mi][ni], 0, 0, 0);

      if (t + 1 < NT) {
        if (t + 2 < NT) {
          if (isA) asm volatile("s_waitcnt vmcnt(4)" ::: "memory");
          else     asm volatile("s_waitcnt vmcnt(2)" ::: "memory");
        } else {
          asm volatile("s_waitcnt vmcnt(0)" ::: "memory");
        }
        __builtin_amdgcn_s_barrier();
      }
    }
  }

#pragma unroll
  for (int mi = 0; mi < 4; ++mi) {
#pragma unroll
    for (int ni = 0; ni < 2; ++ni) {
      int gcol = bcol + wc + ni * 16 + fr;
      float bv = 0.0f;
      if constexpr (HAS_BIAS) bv = bias[(long)z1 * sBias + gcol];
#pragma unroll
      for (int v = 0; v < 4; ++v) {
        int grow = brow + wr + mi * 16 + (lane >> 4) * 4 + v;
        float val = acc0[mi][ni][v] + bv;
        if constexpr (PROD == 3) val += acc1[mi][ni][v] * 0.000244140625f;
        if constexpr (EPI == 0) {
          Cf[coff + (long)grow * ldcf + gcol] = val;
        } else if constexpr (EPI == 1) {
          _Float16 hh = (_Float16)val;
          _Float16 ll = (_Float16)((val - (float)hh) * 4096.0f);
          long ci = coff + (long)grow * ldch + gcol;
          Ch[ci] = hh; Cl[ci] = ll;
        } else if constexpr (EPI == 3) {
          Ch[coff + (long)grow * ldch + gcol] = (_Float16)val;
        } else {
          if (bcol < 2048) {       // uniform per block
            _Float16 hh = (_Float16)val;
            _Float16 ll = (_Float16)((val - (float)hh) * 4096.0f);
            long ci = (long)grow * ldch + gcol;
            Ch[ci] = hh; Cl[ci] = ll;
          } else {
            Cf[(long)grow * ldcf + (gcol - 2048)] = val;
          }
        }
      }
    }
  }
}

// ---------------------------------------------------------------------------
// bf16 MFMA GEMM (experts): 128x128 tile, K-step 32, 3-STAGE counted-vmcnt
// pipeline (T4, verified R15), bank-swizzled LDS, 48KB.  Z = expert index.
// IND_A (R18): A rows gathered through tfs (slot -> token row of A, or zero
// row if slot empty) — fuses the former dispatch_rows kernel into staging.
// T5 probe (R18): s_setprio(1/0) around the MFMA cluster.
// ---------------------------------------------------------------------------
template<bool OUT_BF16, bool HAS_BIAS, bool IND_A>
__global__ __launch_bounds__(256) void bgemm16(
    const bf16_t* __restrict__ A, const bf16_t* __restrict__ B,
    void* __restrict__ Cout, const float* __restrict__ bias,
    int K, long lda, long ldb, long ldc,
    long sA1, long sB1, long sC1, long sBias,
    const int* __restrict__ tfs, const bf16_t* __restrict__ zrow)
{
  __shared__ bf16_t tiles[2][3][128 * 32];
  const int z = blockIdx.z;
  const long coff = (long)z * sC1;
  const int brow = blockIdx.y * 128, bcol = blockIdx.x * 128;
  const int tid = threadIdx.x, lane = tid & 63, wid = tid >> 6;
  const int wr = (wid >> 1) * 64, wc = (wid & 1) * 64;
  const int fr = lane & 15;
  const int fqs = (((lane >> 4) ^ ((fr >> 1) & 3)) * 8);

  const int tsel = wid >> 1, halfsel = wid & 1;

  // per-chunk source base pointers (4 chunks of 16 rows each per wave)
  const bf16_t* cbase[4];
#pragma unroll
  for (int i = 0; i < 4; ++i) {
    if (tsel == 0) {
      int row_i = brow + 64 * halfsel + 16 * i + (lane >> 2);
      if constexpr (IND_A) {
        int tok = tfs[z * CAP_ + row_i];
        cbase[i] = ((tok >= 0) ? (A + (long)tok * 1024) : zrow) + SRC_SWZ(lane) * 8;
      } else {
        cbase[i] = A + (long)z * sA1 + (long)row_i * lda + SRC_SWZ(lane) * 8;
      }
    } else {
      int row_i = bcol + 64 * halfsel + 16 * i + (lane >> 2);
      cbase[i] = B + (long)z * sB1 + (long)row_i * ldb + SRC_SWZ(lane) * 8;
    }
  }

  f32x4 acc[4][4];
#pragma unroll
  for (int mi = 0; mi < 4; ++mi)
#pragma unroll
    for (int ni = 0; ni < 4; ++ni)
      acc[mi][ni] = f32x4{0.0f, 0.0f, 0.0f, 0.0f};

  const int NT = K >> 5;

  // prologue: tiles 0,1 issued; drain tile 0 (leave 4 of tile 1 in flight)
#pragma unroll
  for (int i = 0; i < 4; ++i)
    gload16(cbase[i], &tiles[tsel][0][(4 * halfsel + i) * 512]);
#pragma unroll
  for (int i = 0; i < 4; ++i)
    gload16(cbase[i] + 32, &tiles[tsel][1][(4 * halfsel + i) * 512]);
  asm volatile("s_waitcnt vmcnt(4)" ::: "memory");
  __builtin_amdgcn_s_barrier();

  for (int t = 0; t < NT; ++t) {
    const int b = t % 3;
    if (t + 2 < NT) {
      const int k2 = (t + 2) * 32;
      const int b2 = (t + 2) % 3;
#pragma unroll
      for (int i = 0; i < 4; ++i)
        gload16(cbase[i] + k2, &tiles[tsel][b2][(4 * halfsel + i) * 512]);
    }

    bf16x8 af[4], bfv[4];
#pragma unroll
    for (int i = 0; i < 4; ++i) {
      af[i]  = *(const bf16x8*)&tiles[0][b][(wr + i * 16 + fr) * 32 + fqs];
      bfv[i] = *(const bf16x8*)&tiles[1][b][(wc + i * 16 + fr) * 32 + fqs];
    }
    __builtin_amdgcn_s_setprio(1);
#pragma unroll
    for (int mi = 0; mi < 4; ++mi)
#pragma unroll
      for (int ni = 0; ni < 4; ++ni)
        acc[mi][ni] = __builtin_amdgcn_mfma_f32_16x16x32_bf16(af[mi], bfv[ni], acc[mi][ni], 0, 0, 0);
    __builtin_amdgcn_s_setprio(0);

    if (t + 1 < NT) {
      if (t + 2 < NT) asm volatile("s_waitcnt vmcnt(4)" ::: "memory");
      else            asm volatile("s_waitcnt vmcnt(0)" ::: "memory");
      __builtin_amdgcn_s_barrier();
    }
  }

#pragma unroll
  for (int mi = 0; mi < 4; ++mi) {
#pragma unroll
    for (int ni = 0; ni < 4; ++ni) {
      int gcol = bcol + wc + ni * 16 + fr;
      float bv = 0.0f;
      if constexpr (HAS_BIAS) bv = bias[(long)z * sBias + gcol];
#pragma unroll
      for (int v = 0; v < 4; ++v) {
        int grow = brow + wr + mi * 16 + (lane >> 4) * 4 + v;
        float val = acc[mi][ni][v] + bv;
        long ci = coff + (long)grow * ldc + gcol;
        if constexpr (OUT_BF16) ((bf16_t*)Cout)[ci] = (bf16_t)val;
        else                    ((float*)Cout)[ci]  = val;
      }
    }
  }
}

// ---------------------------------------------------------------------------
// 32x32 tiled transpose: dst[c][r] = (TOUT)src[r][c]; z-batched.
// ---------------------------------------------------------------------------
template<typename TOUT>
__global__ __launch_bounds__(256) void transpose_f32(
    const float* __restrict__ src, TOUT* __restrict__ dst,
    long ld_src, long ld_dst, int Z2,
    long ss1, long ss2, long sd1, long sd2)
{
  __shared__ float t[32][33];
  const int z = blockIdx.z, z1 = z / Z2, z2 = z - z1 * Z2;
  src += (long)z1 * ss1 + (long)z2 * ss2;
  dst += (long)z1 * sd1 + (long)z2 * sd2;
  const int c0 = blockIdx.x * 32, r0 = blockIdx.y * 32;
  const int tx = threadIdx.x & 31, ty = threadIdx.x >> 5;
#pragma unroll
  for (int i = 0; i < 4; ++i)
    t[ty + i * 8][tx] = src[(long)(r0 + ty + i * 8) * ld_src + c0 + tx];
  __syncthreads();
#pragma unroll
  for (int i = 0; i < 4; ++i)
    dst[(long)(c0 + ty + i * 8) * ld_dst + r0 + tx] = (TOUT)t[tx][ty + i * 8];
}

// ---------------------------------------------------------------------------
// transpose + split: dsth/dstl[c][r] = f16 limbs of src[r][c]; z-batched.
// ---------------------------------------------------------------------------
__global__ __launch_bounds__(256) void transpose_split(
    const float* __restrict__ src, _Float16* __restrict__ dh, _Float16* __restrict__ dl,
    long ld_src, long ld_dst, int Z2,
    long ss1, long ss2, long sd1, long sd2)
{
  __shared__ float t[32][33];
  const int z = blockIdx.z, z1 = z / Z2, z2 = z - z1 * Z2;
  src += (long)z1 * ss1 + (long)z2 * ss2;
  dh  += (long)z1 * sd1 + (long)z2 * sd2;
  dl  += (long)z1 * sd1 + (long)z2 * sd2;
  const int c0 = blockIdx.x * 32, r0 = blockIdx.y * 32;
  const int tx = threadIdx.x & 31, ty = threadIdx.x >> 5;
#pragma unroll
  for (int i = 0; i < 4; ++i)
    t[ty + i * 8][tx] = src[(long)(r0 + ty + i * 8) * ld_src + c0 + tx];
  __syncthreads();
#pragma unroll
  for (int i = 0; i < 4; ++i) {
    float v = t[tx][ty + i * 8];
    _Float16 h = (_Float16)v;
    _Float16 l = (_Float16)((v - (float)h) * 4096.0f);
    long idx = (long)(c0 + ty + i * 8) * ld_dst + r0 + tx;
    dh[idx] = h;
    dl[idx] = l;
  }
}

// ---------------------------------------------------------------------------
// In-place f16 row softmax (len 1024): scores row -> P row (both f16).
// ---------------------------------------------------------------------------
__global__ __launch_bounds__(256) void softmax16(
    _Float16* __restrict__ Sm, float scale)
{
  __shared__ float red[4];
  const long row = blockIdx.x;
  half4* p = (half4*)(Sm + row * 1024);
  const int tid = threadIdx.x;
  half4 hv = p[tid];
  float v0 = (float)hv.x, v1 = (float)hv.y, v2 = (float)hv.z, v3 = (float)hv.w;
  float m = fmaxf(fmaxf(v0, v1), fmaxf(v2, v3));
#pragma unroll
  for (int o = 32; o; o >>= 1) m = fmaxf(m, __shfl_xor(m, o, 64));
  if ((tid & 63) == 0) red[tid >> 6] = m;
  __syncthreads();
  m = fmaxf(fmaxf(red[0], red[1]), fmaxf(red[2], red[3]));
  __syncthreads();
  float e0 = __expf((v0 - m) * scale);
  float e1 = __expf((v1 - m) * scale);
  float e2 = __expf((v2 - m) * scale);
  float e3 = __expf((v3 - m) * scale);
  float s = e0 + e1 + e2 + e3;
#pragma unroll
  for (int o = 32; o; o >>= 1) s += __shfl_xor(s, o, 64);
  if ((tid & 63) == 0) red[tid >> 6] = s;
  __syncthreads();
  s = red[0] + red[1] + red[2] + red[3];
  float inv = 1.0f / s;
  half4 w;
  w.x = (_Float16)(e0 * inv); w.y = (_Float16)(e1 * inv);
  w.z = (_Float16)(e2 * inv); w.w = (_Float16)(e3 * inv);
  p[tid] = w;
}

// ---------------------------------------------------------------------------
// Row softmax (len 1024) fp32 IN PLACE -> packed f16 limb pair (patch path).
// ---------------------------------------------------------------------------
template<bool WRITE_LO>
__global__ __launch_bounds__(256) void softmax_pack(
    float* __restrict__ Sm, float scale)
{
  __shared__ float red[4];
  const long row = blockIdx.x;
  const float4* p = (const float4*)(Sm + row * 1024);
  const int tid = threadIdx.x;
  float4 v = p[tid];
  float m = fmaxf(fmaxf(v.x, v.y), fmaxf(v.z, v.w));
#pragma unroll
  for (int o = 32; o; o >>= 1) m = fmaxf(m, __shfl_xor(m, o, 64));
  if ((tid & 63) == 0) red[tid >> 6] = m;
  __syncthreads();
  m = fmaxf(fmaxf(red[0], red[1]), fmaxf(red[2], red[3]));
  __syncthreads();
  float e0 = __expf((v.x - m) * scale);
  float e1 = __expf((v.y - m) * scale);
  float e2 = __expf((v.z - m) * scale);
  float e3 = __expf((v.w - m) * scale);
  float s = e0 + e1 + e2 + e3;
#pragma unroll
  for (int o = 32; o; o >>= 1) s += __shfl_xor(s, o, 64);
  if ((tid & 63) == 0) red[tid >> 6] = s;
  __syncthreads();
  s = red[0] + red[1] + red[2] + red[3];
  float inv = 1.0f / s;
  float p0 = e0 * inv, p1 = e1 * inv, p2 = e2 * inv, p3 = e3 * inv;
  half4 h;
  h.x = (_Float16)p0; h.y = (_Float16)p1; h.z = (_Float16)p2; h.w = (_Float16)p3;
  _Float16* base = (_Float16*)Sm + row * 2048;
  ((half4*)base)[tid] = h;
  if constexpr (WRITE_LO) {
    half4 l;
    l.x = (_Float16)((p0 - (float)h.x) * 4096.0f);
    l.y = (_Float16)((p1 - (float)h.y) * 4096.0f);
    l.z = (_Float16)((p2 - (float)h.z) * 4096.0f);
    l.w = (_Float16)((p3 - (float)h.w) * 4096.0f);
    ((half4*)(base + 1024))[tid] = l;
  }
}

// ---------------------------------------------------------------------------
// Fused: y1 = LN(x + attn) -> bf16 y1b; gate logits, argmax idx, gval;
// borderline tokens (gap < TAU) appended to per-sequence lists (cap 128).
// ---------------------------------------------------------------------------
__global__ __launch_bounds__(256) void add_ln_gate(
    const float* __restrict__ x, const float* __restrict__ attn,
    const float* __restrict__ g, const float* __restrict__ be,
    const float* __restrict__ wg, bf16_t* __restrict__ yb,
    int* __restrict__ idx, float* __restrict__ gval,
    int* __restrict__ bcnt16, int* __restrict__ blist16)
{
  __shared__ float red[4];
  __shared__ float lred[4][8];
  const long s = blockIdx.x;
  const int tid = threadIdx.x;
  const int lane = tid & 63, w = tid >> 6;
  float4 va = ((const float4*)(x + s * 1024))[tid];
  float4 vb = ((const float4*)(attn + s * 1024))[tid];
  float v0 = va.x + vb.x, v1 = va.y + vb.y, v2 = va.z + vb.z, v3 = va.w + vb.w;
  float sum = v0 + v1 + v2 + v3;
#pragma unroll
  for (int o = 32; o; o >>= 1) sum += __shfl_xor(sum, o, 64);
  if (lane == 0) red[w] = sum;
  __syncthreads();
  float mu = (red[0] + red[1] + red[2] + red[3]) * (1.0f / 1024.0f);
  __syncthreads();
  float d0 = v0 - mu, d1 = v1 - mu, d2 = v2 - mu, d3 = v3 - mu;
  float ss = d0 * d0 + d1 * d1 + d2 * d2 + d3 * d3;
#pragma unroll
  for (int o = 32; o; o >>= 1) ss += __shfl_xor(ss, o, 64);
  if (lane == 0) red[w] = ss;
  __syncthreads();
  float var = (red[0] + red[1] + red[2] + red[3]) * (1.0f / 1024.0f);
  float rstd = rsqrtf(var + 1e-5f);
  float4 vg  = ((const float4*)g)[tid];
  float4 vbe = ((const float4*)be)[tid];
  float y0 = d0 * rstd * vg.x + vbe.x;
  float y1v = d1 * rstd * vg.y + vbe.y;
  float y2v = d2 * rstd * vg.z + vbe.z;
  float y3 = d3 * rstd * vg.w + vbe.w;
  bf16x4 ov = { (bf16_t)y0, (bf16_t)y1v, (bf16_t)y2v, (bf16_t)y3 };
  *(bf16x4*)(yb + s * 1024 + tid * 4) = ov;
  float lg[8];
  const float* w0 = wg + (long)(tid * 4) * 8;
#pragma unroll
  for (int e = 0; e < 8; ++e)
    lg[e] = y0 * w0[e] + y1v * w0[8 + e] + y2v * w0[16 + e] + y3 * w0[24 + e];
#pragma unroll
  for (int e = 0; e < 8; ++e) {
#pragma unroll
    for (int o = 32; o; o >>= 1) lg[e] += __shfl_xor(lg[e], o, 64);
  }
  if (lane == 0) {
#pragma unroll
    for (int e = 0; e < 8; ++e) lred[w][e] = lg[e];
  }
  __syncthreads();
  if (tid == 0) {
    float Lg[8];
#pragma unroll
    for (int e = 0; e < 8; ++e)
      Lg[e] = lred[0][e] + lred[1][e] + lred[2][e] + lred[3][e];
    float best = Lg[0], second = -1e30f; int bi = 0;
#pragma unroll
    for (int e = 1; e < 8; ++e) {
      if (Lg[e] > best) { second = best; best = Lg[e]; bi = e; }
      else if (Lg[e] > second) second = Lg[e];
    }
    float sm = 0.0f;
#pragma unroll
    for (int e = 0; e < 8; ++e) sm += __expf(Lg[e] - best);
    idx[s] = bi;
    gval[s] = 1.0f / sm;
    if (best - second < TAU_) {
      int n = (int)(s & 15);
      int p = atomicAdd(&bcnt16[n], 1);
      if (p < 128) blist16[n * 128 + p] = (int)s;
    }
  }
}

// ---------------------------------------------------------------------------
__global__ void zero16(int* __restrict__ p)
{
  if (threadIdx.x < 16) p[threadIdx.x] = 0;
}

// ---------------------------------------------------------------------------
// Gather borderline Q rows (limbs) into padded [16*128][1024]; pad rows zero.
// ---------------------------------------------------------------------------
__global__ __launch_bounds__(64) void qp_gather(
    const int* __restrict__ bcnt16, const int* __restrict__ blist16,
    const _Float16* __restrict__ QKh, const _Float16* __restrict__ QKl,
    _Float16* __restrict__ Qph, _Float16* __restrict__ Qpl)
{
  const int b = blockIdx.x;
  const int n = b >> 7, p = b & 127;
  const int t = threadIdx.x;
  half8* dh = (half8*)(Qph + (long)b * 1024);
  half8* dl = (half8*)(Qpl + (long)b * 1024);
  int cnt = bcnt16[n]; if (cnt > 128) cnt = 128;
  if (p < cnt) {
    long srow = (long)blist16[b] * 2048;
    const half8* sh = (const half8*)(QKh + srow);
    const half8* sl = (const half8*)(QKl + srow);
    dh[t * 2]     = sh[t * 2];
    dh[t * 2 + 1] = sh[t * 2 + 1];
    dl[t * 2]     = sl[t * 2];
    dl[t * 2 + 1] = sl[t * 2 + 1];
  } else {
    half8 z;
#pragma unroll
    for (int i = 0; i < 8; ++i) z[i] = (_Float16)0.0f;
    dh[t * 2] = z; dh[t * 2 + 1] = z;
    dl[t * 2] = z; dl[t * 2 + 1] = z;
  }
}

// ---------------------------------------------------------------------------
// Final fix: exact y1 row + logits from exact attn_p; overwrite idx/gval.
// ---------------------------------------------------------------------------
__global__ __launch_bounds__(256) void gate_fix(
    const int* __restrict__ bcnt16, const int* __restrict__ blist16,
    const float* __restrict__ attn_p, const float* __restrict__ x,
    const float* __restrict__ g, const float* __restrict__ be,
    const float* __restrict__ wg,
    int* __restrict__ idx, float* __restrict__ gval)
{
  const int b = blockIdx.x;
  const int n = b >> 7, p = b & 127;
  int cnt = bcnt16[n]; if (cnt > 128) cnt = 128;
  if (p >= cnt) return;
  const long s = blist16[b];
  __shared__ float red[4];
  __shared__ float lred[4][8];
  const int tid = threadIdx.x;
  const int lane = tid & 63, w = tid >> 6;
  float4 va = ((const float4*)(x + s * 1024))[tid];
  float4 vb = ((const float4*)(attn_p + (long)b * 1024))[tid];
  float v0 = va.x + vb.x, v1 = va.y + vb.y, v2 = va.z + vb.z, v3 = va.w + vb.w;
  float sum = v0 + v1 + v2 + v3;
#pragma unroll
  for (int o = 32; o; o >>= 1) sum += __shfl_xor(sum, o, 64);
  if (lane == 0) red[w] = sum;
  __syncthreads();
  float mu = (red[0] + red[1] + red[2] + red[3]) * (1.0f / 1024.0f);
  __syncthreads();
  float d0 = v0 - mu, d1 = v1 - mu, d2 = v2 - mu, d3 = v3 - mu;
  float ss = d0 * d0 + d1 * d1 + d2 * d2 + d3 * d3;
#pragma unroll
  for (int o = 32; o; o >>= 1) ss += __shfl_xor(ss, o, 64);
  if (lane == 0) red[w] = ss;
  __syncthreads();
  float var = (red[0] + red[1] + red[2] + red[3]) * (1.0f / 1024.0f);
  float rstd = rsqrtf(var + 1e-5f);
  float4 vg  = ((const float4*)g)[tid];
  float4 vbe = ((const float4*)be)[tid];
  float y0 = d0 * rstd * vg.x + vbe.x;
  float y1v = d1 * rstd * vg.y + vbe.y;
  float y2v = d2 * rstd * vg.z + vbe.z;
  float y3 = d3 * rstd * vg.w + vbe.w;
  float lg[8];
  const float* w0 = wg + (long)(tid * 4) * 8;
#pragma unroll
  for (int e = 0; e < 8; ++e)
    lg[e] = y0 * w0[e] + y1v * w0[8 + e] + y2v * w0[16 + e] + y3 * w0[24 + e];
#pragma unroll
  for (int e = 0; e < 8; ++e) {
#pragma unroll
    for (int o = 32; o; o >>= 1) lg[e] += __shfl_xor(lg[e], o, 64);
  }
  if (lane == 0) {
#pragma unroll
    for (int e = 0; e < 8; ++e) lred[w][e] = lg[e];
  }
  __syncthreads();
  if (tid == 0) {
    float Lg[8];
#pragma unroll
    for (int e = 0; e < 8; ++e)
      Lg[e] = lred[0][e] + lred[1][e] + lred[2][e] + lred[3][e];
    float best = Lg[0]; int bi = 0;
#pragma unroll
    for (int e = 1; e < 8; ++e) { if (Lg[e] > best) { best = Lg[e]; bi = e; } }
    float sm = 0.0f;
#pragma unroll
    for (int e = 0; e < 8; ++e) sm += __expf(Lg[e] - best);
    idx[s] = bi;
    gval[s] = 1.0f / sm;
  }
}

// ---------------------------------------------------------------------------
// out = LN(y1b + (keep ? gval * ymoe[slot] : 0); g, be)   [bf16 inputs]
// ---------------------------------------------------------------------------
__global__ __launch_bounds__(256) void combine_ln(
    const bf16_t* __restrict__ y1b, const bf16_t* __restrict__ ymoe,
    const int* __restrict__ slot, const float* __restrict__ gval,
    const float* __restrict__ g, const float* __restrict__ be,
    float* __restrict__ out)
{
  __shared__ float red[4];
  const long s = blockIdx.x;
  const int tid = threadIdx.x;
  const int lane = tid & 63, w = tid >> 6;
  int sl = slot[s];
  bool keep = sl < ESLOTS_;
  float gv = keep ? gval[s] : 0.0f;
  long mrow = keep ? (long)sl * 1024 : 0;
  bf16x4 ya = *(const bf16x4*)(y1b + s * 1024 + tid * 4);
  bf16x4 ym = *(const bf16x4*)(ymoe + mrow + tid * 4);
  float v0 = (float)ya[0] + gv * (float)ym[0];
  float v1 = (float)ya[1] + gv * (float)ym[1];
  float v2 = (float)ya[2] + gv * (float)ym[2];
  float v3 = (float)ya[3] + gv * (float)ym[3];
  float sum = v0 + v1 + v2 + v3;
#pragma unroll
  for (int o = 32; o; o >>= 1) sum += __shfl_xor(sum, o, 64);
  if (lane == 0) red[w] = sum;
  __syncthreads();
  float mu = (red[0] + red[1] + red[2] + red[3]) * (1.0f / 1024.0f);
  __syncthreads();
  float d0 = v0 - mu, d1 = v1 - mu, d2 = v2 - mu, d3 = v3 - mu;
  float ss = d0 * d0 + d1 * d1 + d2 * d2 + d3 * d3;
#pragma unroll
  for (int o = 32; o; o >>= 1) ss += __shfl_xor(ss, o, 64);
  if (lane == 0) red[w] = ss;
  __syncthreads();
  float var = (red[0] + red[1] + red[2] + red[3]) * (1.0f / 1024.0f);
  float rstd = rsqrtf(var + 1e-5f);
  float4 vg  = ((const float4*)g)[tid];
  float4 vbe = ((const float4*)be)[tid];
  float4 ov = {d0 * rstd * vg.x + vbe.x, d1 * rstd * vg.y + vbe.y,
               d2 * rstd * vg.z + vbe.z, d3 * rstd * vg.w + vbe.w};
  ((float4*)(out + s * 1024))[tid] = ov;
}

// ---------------------------------------------------------------------------
// Parallel routing scan (R17), token-order-exact, 3 kernels.
// ---------------------------------------------------------------------------
__global__ __launch_bounds__(128) void rs_count(
    const int* __restrict__ idx, int* __restrict__ bcounts, int* __restrict__ tfs)
{
  __shared__ int cnt[8];
  const int b = blockIdx.x, t = threadIdx.x;
  if (t < 8) cnt[t] = 0;
  __syncthreads();
  int e = idx[b * 128 + t];
  atomicAdd(&cnt[e], 1);
  tfs[b * 128 + t] = -1;
  __syncthreads();
  if (t < 8) bcounts[b * 8 + t] = cnt[t];
}

__global__ __launch_bounds__(64) void rs_scan(
    const int* __restrict__ bcounts, int* __restrict__ boffs)
{
  const int e = threadIdx.x;
  if (e < 8) {
    int acc = 0;
    for (int b = 0; b < 128; ++b) {
      boffs[b * 8 + e] = acc;
      acc += bcounts[b * 8 + e];
    }
  }
}

__global__ __launch_bounds__(128) void rs_emit(
    const int* __restrict__ idx, const int* __restrict__ boffs,
    int* __restrict__ slot, int* __restrict__ tfs)
{
  __shared__ int le[128];
  const int b = blockIdx.x, t = threadIdx.x;
  const int s = b * 128 + t;
  int e = idx[s];
  le[t] = e;
  __syncthreads();
  int loc = boffs[b * 8 + e];
  for (int u = 0; u < t; ++u) loc += (le[u] == e) ? 1 : 0;
  int sl = (loc < CAP_) ? e * CAP_ + loc : ESLOTS_;
  slot[s] = sl;
  if (sl < ESLOTS_) tfs[sl] = s;
}

// ---------------------------------------------------------------------------
__global__ void fill_val(float* __restrict__ p, float v, long n)
{
  long i = (long)blockIdx.x * blockDim.x + threadIdx.x;
  long stride = (long)gridDim.x * blockDim.x;
  for (; i < n; i += stride) p[i] = v;
}

// ---------------------------------------------------------------------------
extern "C" void kernel_launch(void* const* d_in, const int* in_sizes, int n_in,
                              void* d_out, int out_size, void* d_ws, size_t ws_size,
                              hipStream_t stream)
{
  const float* x    = (const float*)d_in[0];
  const float* Wqkv = (const float*)d_in[1];
  const float* bqkv = (const float*)d_in[2];
  const float* Wo   = (const float*)d_in[3];
  const float* bo   = (const float*)d_in[4];
  const float* g1   = (const float*)d_in[5];
  const float* b1n  = (const float*)d_in[6];
  const float* g2   = (const float*)d_in[7];
  const float* b2n  = (const float*)d_in[8];
  const float* wg   = (const float*)d_in[9];
  const float* w1   = (const float*)d_in[10];
  const float* b1e  = (const float*)d_in[11];
  const float* w2   = (const float*)d_in[12];
  const float* b2e  = (const float*)d_in[13];
  float* out = (float*)d_out;

  const size_t MB = 1ull << 20;
  const size_t REQUIRED = 384 * MB;
  if (ws_size < REQUIRED) {
    fill_val<<<2048, 256, 0, stream>>>(out, (float)(ws_size >> 20), (long)out_size);
    return;
  }

  char* ws = (char*)d_ws;
  // Region map v4 (audited) — same as R15/R17 (+zrow at 337MB):
  _Float16* Xh   = (_Float16*)(ws + 0);
  _Float16* Xl   = (_Float16*)(ws + 32 * MB);
  _Float16* Wqh  = (_Float16*)(ws + 64 * MB);
  _Float16* Wql  = (_Float16*)(ws + 70 * MB);
  _Float16* scores16 = (_Float16*)(ws + 0);
  _Float16* Woh  = (_Float16*)(ws + 64 * MB);
  _Float16* Wol  = (_Float16*)(ws + 66 * MB);
  _Float16* QKh  = (_Float16*)(ws + 80 * MB);
  _Float16* QKl  = (_Float16*)(ws + 144 * MB);
  float*    Vf32 = (float*)(ws + 208 * MB);
  _Float16* oh   = (_Float16*)(ws + 208 * MB);
  _Float16* vTh  = (_Float16*)(ws + 272 * MB);
  _Float16* vTl  = (_Float16*)(ws + 304 * MB);
  float*    attn = (float*)(ws + 0);
  bf16_t*   y1b  = (bf16_t*)(ws + 208 * MB);
  float*    scp   = (float*)(ws + 0);             // 32MB patch scores
  _Float16* Qph   = (_Float16*)(ws + 32 * MB);
  _Float16* Qpl   = (_Float16*)(ws + 36 * MB);
  _Float16* o_ph  = (_Float16*)(ws + 40 * MB);
  _Float16* o_pl  = (_Float16*)(ws + 44 * MB);
  float*    attnp = (float*)(ws + 48 * MB);
  int*      idx  = (int*)(ws + 336 * MB);
  int*      slot = idx + S_;
  float*    gval = (float*)(slot + S_);
  int*      tfs  = (int*)(gval + S_);
  int*      bcnt16  = tfs + S_;
  int*      blist16 = bcnt16 + 16;
  int*      bcounts = blist16 + 2048;   // 128*8 ints
  int*      boffs   = bcounts + 1024;   // 128*8 ints
  bf16_t*   zrow = (bf16_t*)(ws + 337 * MB);   // 2KB zero row
  bf16_t*   W1t  = (bf16_t*)(ws + 0);
  bf16_t*   W2t  = (bf16_t*)(ws + 0);
  bf16_t*   h    = (bf16_t*)(ws + 80 * MB);
  bf16_t*   ymoe = (bf16_t*)(ws + 304 * MB);

  // 0. zero borderline counters + zero row early
  zero16<<<1, 64, 0, stream>>>(bcnt16);
  fill_val<<<1, 256, 0, stream>>>((float*)zrow, 0.0f, 512);

  // 1. pre-split x and Wqkv to f16 limbs
  split2<<<4096, 256, 0, stream>>>(x, Xh, Xl, (long)S_ * D_ / 4);
  split2<<<2048, 256, 0, stream>>>(Wqkv, Wqh, Wql, (long)3 * D_ * D_ / 4);

  // 2. qkv GEMM (3-product, 2-phase as verified R15): Q,K -> limbs; V -> fp32
  hgemm3s<2, true, 3><<<dim3(48, 128, 1), 256, 0, stream>>>(
      Xh, Xl, Wqh, Wql, Vf32, QKh, QKl, bqkv,
      D_, D_, D_, D_, 2 * D_,
      1, 0, 0, 0, 0, 0, 0, 0);

  // 3. split Wo
  split2<<<1024, 256, 0, stream>>>(Wo, Woh, Wol, (long)D_ * D_ / 4);

  // 4. vT limbs [n,h][HD][L] from Vf32 [S][D]
  transpose_split<<<dim3(HD_ / 32, L_ / 32, 64), 256, 0, stream>>>(
      Vf32, vTh, vTl, (long)N_ * D_, L_,
      H_, D_, HD_, (long)H_ * HD_ * L_, (long)HD_ * L_);

  // 5. attention main path (1-product f16, 3-stage pipeline), 2 groups of 8
  for (int g = 0; g < 2; ++g) {
    const long qko = (long)g * 8 * 2048;
    hgemm3s<3, false, 1><<<dim3(16, 8, 32), 256, 0, stream>>>(
        QKh + qko, QKl + qko, QKh + qko + 1024, QKl + qko + 1024,
        nullptr, scores16, nullptr, nullptr,
        HD_, (long)N_ * 2048, (long)N_ * 2048, 0, L_,
        H_, 2048, 256, 2048, 256, (long)H_ * L_ * L_, (long)L_ * L_, 0);
    softmax16<<<8 * H_ * L_, 256, 0, stream>>>(scores16, 0.0625f);
    hgemm3s<3, false, 1><<<dim3(4, 8, 32), 256, 0, stream>>>(
        scores16, nullptr,
        vTh + (long)g * 8 * H_ * HD_ * L_, vTl + (long)g * 8 * H_ * HD_ * L_,
        nullptr, oh + (long)g * 8 * D_, nullptr, nullptr,
        L_, L_, L_, 0, (long)N_ * D_,
        H_, (long)H_ * L_ * L_, (long)L_ * L_,
        (long)H_ * HD_ * L_, (long)HD_ * L_, D_, HD_, 0);
  }

  // 6. attn = o @ Wo^T + bo   (1-product, 3-stage)
  hgemm3s<0, true, 1><<<dim3(16, 128, 1), 256, 0, stream>>>(
      oh, nullptr, Woh, Wol, attn, nullptr, nullptr, bo,
      D_, D_, D_, D_, 0,
      1, 0, 0, 0, 0, 0, 0, 0);

  // 7. fused LN + gate + borderline detection (writes y1b bf16)
  add_ln_gate<<<S_, 256, 0, stream>>>(x, attn, g1, b1n, wg, y1b,
                                      idx, gval, bcnt16, blist16);

  // 8. exact-gate patch for borderline tokens (3-product grade, 2-phase)
  qp_gather<<<2048, 64, 0, stream>>>(bcnt16, blist16, QKh, QKl, Qph, Qpl);
  hgemm3s<0, false, 3><<<dim3(16, 1, 64), 256, 0, stream>>>(
      Qph, Qpl, QKh + 1024, QKl + 1024, scp, nullptr, nullptr, nullptr,
      HD_, 1024, (long)N_ * 2048, 1024, 0,
      4, (long)128 * 1024, 256, 2048, 256,
      (long)4 * 128 * 1024, (long)128 * 1024, 0);
  softmax_pack<true><<<64 * 128, 256, 0, stream>>>(scp, 0.0625f);
  hgemm3s<1, false, 3><<<dim3(4, 1, 64), 256, 0, stream>>>(
      (_Float16*)scp, (_Float16*)scp + 1024, vTh, vTl,
      nullptr, o_ph, o_pl, nullptr,
      L_, 2048, L_, 0, 1024,
      4, (long)4 * 128 * 2048, (long)128 * 2048,
      (long)H_ * HD_ * L_, (long)HD_ * L_,
      (long)128 * 1024, 256, 0);
  hgemm3s<0, true, 3><<<dim3(16, 16, 1), 256, 0, stream>>>(
      o_ph, o_pl, Woh, Wol, attnp, nullptr, nullptr, bo,
      D_, D_, D_, D_, 0,
      1, 0, 0, 0, 0, 0, 0, 0);
  gate_fix<<<2048, 256, 0, stream>>>(bcnt16, blist16, attnp, x,
                                     g1, b1n, wg, idx, gval);

  // 9. token-order routing scan + capacity drop (parallel, 3 kernels)
  rs_count<<<128, 128, 0, stream>>>(idx, bcounts, tfs);
  rs_scan<<<1, 64, 0, stream>>>(bcounts, boffs);
  rs_emit<<<128, 128, 0, stream>>>(idx, boffs, slot, tfs);

  // 10. W1t[e][FF][D] bf16 from w1 fp32 (patch scratch dead)
  transpose_f32<bf16_t><<<dim3(FF_ / 32, D_ / 32, E_), 256, 0, stream>>>(
      w1, W1t, FF_, D_, 1, (long)D_ * FF_, 0, (long)FF_ * D_, 0);

  // 11. h[e] = gather(y1b via tfs) @ w1[e] + b1[e]; fused dispatch (IND_A)
  bgemm16<true, true, true><<<dim3(32, 16, 8), 256, 0, stream>>>(
      y1b, W1t, h, b1e, D_, D_, D_, FF_,
      0, (long)FF_ * D_, (long)CAP_ * FF_, FF_, tfs, zrow);

  // 12. W2t[e][D][FF] bf16 from w2 fp32
  transpose_f32<bf16_t><<<dim3(D_ / 32, FF_ / 32, E_), 256, 0, stream>>>(
      w2, W2t, D_, FF_, 1, (long)FF_ * D_, 0, (long)D_ * FF_, 0);

  // 13. ymoe[e] (bf16) = h[e] @ w2[e] + b2[e]
  bgemm16<true, true, false><<<dim3(8, 16, 8), 256, 0, stream>>>(
      h, W2t, ymoe, b2e, FF_, FF_, FF_, D_,
      (long)CAP_ * FF_, (long)D_ * FF_, (long)CAP_ * D_, D_, nullptr, nullptr);

  // 14. out = LN(y1b + combine)
  combine_ln<<<S_, 256, 0, stream>>>(y1b, ymoe, slot, gval, g2, b2n, out);
}